// Round 1
// baseline (741.172 us; speedup 1.0000x reference)
//
#include <hip/hip_runtime.h>
#include <hip/hip_bf16.h>
#include <stdint.h>

// Problem constants
#define S_DIM 4096
#define D_DIM 1024
#define KAUG  1088          // 1024 + 64 (LoRA-augmented K)
#define M_ROWS 8192         // B*S

typedef short bf16x8 __attribute__((ext_vector_type(8)));
typedef float f32x4  __attribute__((ext_vector_type(4)));

__device__ __forceinline__ f32x4 mfma16(bf16x8 a, bf16x8 b, f32x4 c) {
  return __builtin_amdgcn_mfma_f32_16x16x32_bf16(a, b, c, 0, 0, 0);
}
__device__ __forceinline__ short f2bs(float f) {
  __hip_bfloat16 h = __float2bfloat16(f);
  return *reinterpret_cast<short*>(&h);
}
__device__ __forceinline__ float bs2f(short s) {
  __hip_bfloat16 h;
  *reinterpret_cast<short*>(&h) = s;
  return __bfloat162float(h);
}
__device__ __forceinline__ void gload16(const void* g, void* l) {
  __builtin_amdgcn_global_load_lds(
      (const __attribute__((address_space(1))) unsigned int*)g,
      (__attribute__((address_space(3))) unsigned int*)l, 16, 0, 0);
}

// ---------------- prep: casts + augmented operand construction ----------------
// regions (flat grid-stride, 1 elem/thread):
//  R1 xaug cols 0..1023 <- bf16(x)              8192*1024
//  R2 wqkv_aug (3072 x 1088)                     3072*1088
//  R3 wo_aug  (1024 x 1088)                      1024*1088
//  R4 l1cat   (64 x 1024)  rows: lq1,lk1,lv1,lo1 65536
//  R5 bias_cat (3072)                            3072
__global__ void prep_k(const float* __restrict__ x,
                       const float* __restrict__ wq, const float* __restrict__ wk,
                       const float* __restrict__ wv, const float* __restrict__ wo,
                       const float* __restrict__ wqb,
                       const float* __restrict__ lq1, const float* __restrict__ lq2,
                       const float* __restrict__ lk1, const float* __restrict__ lk2,
                       const float* __restrict__ lv1, const float* __restrict__ lv2,
                       const float* __restrict__ lo1, const float* __restrict__ lo2,
                       short* __restrict__ xaug, short* __restrict__ wqkv,
                       short* __restrict__ woaug, short* __restrict__ l1cat,
                       float* __restrict__ biasc)
{
  unsigned i = blockIdx.x * 256u + threadIdx.x;
  if (i < 8388608u) {   // R1
    unsigned m = i >> 10, k = i & 1023u;
    xaug[(size_t)m * KAUG + k] = f2bs(x[i]);
    return;
  }
  i -= 8388608u;
  if (i < 3342336u) {   // R2
    unsigned n = i / 1088u, k = i - n * 1088u;
    float v;
    if (k < 1024u) {
      v = (n < 1024u) ? wq[n * 1024u + k]
        : (n < 2048u) ? wk[(n - 1024u) * 1024u + k]
                      : wv[(n - 2048u) * 1024u + k];
    } else {
      unsigned r = k - 1024u, blk = r >> 4, which = n >> 10;
      if (blk == which) {
        const float* l2 = which == 0 ? lq2 : which == 1 ? lk2 : lv2;
        v = l2[(n & 1023u) * 16u + (r & 15u)];
      } else v = 0.f;
    }
    wqkv[i] = f2bs(v);
    return;
  }
  i -= 3342336u;
  if (i < 1114112u) {   // R3
    unsigned n = i / 1088u, k = i - n * 1088u;
    float v = (k < 1024u) ? wo[n * 1024u + k]
            : (k < 1040u) ? lo2[n * 16u + (k - 1024u)] : 0.f;
    woaug[i] = f2bs(v);
    return;
  }
  i -= 1114112u;
  if (i < 65536u) {     // R4
    unsigned r = i >> 10, k = i & 1023u;
    const float* src = r < 16u ? lq1 : r < 32u ? lk1 : r < 48u ? lv1 : lo1;
    l1cat[i] = f2bs(src[(r & 15u) * 1024u + k]);
    return;
  }
  i -= 65536u;
  if (i < 3072u) {      // R5
    biasc[i] = (i < 1024u) ? wqb[i] : 0.f;
  }
}

// ---------------- GEMM: C[m,n] = sum_k A[m,k]*B[n,k]  (B^T layout) -----------
// 128x128 tile, BK=32, 4 waves each 64x64, m97 structure.
// MODE 0: fp32 out + bias      MODE 1: bf16 out at [m*ldc + colofs + n]
// MODE 2: QKV scatter to (B,H,S,HD) bf16 buffers + bias_cat
template<int MODE>
__global__ __launch_bounds__(256) void gemm_bt(
    const short* __restrict__ A, int lda,
    const short* __restrict__ B, int ldb,
    int N, int K,
    const float* __restrict__ bias,
    void* __restrict__ Cout, int ldc, int colofs,
    short* __restrict__ qo, short* __restrict__ ko, short* __restrict__ vo)
{
  __shared__ short As[128 * 32];
  __shared__ short Bs[128 * 32];
  const int tid = threadIdx.x;
  const int w = tid >> 6, lane = tid & 63;
  const int q4 = lane >> 4, c = lane & 15;
  const int mh = w >> 1, nh = w & 1;
  const int mt = blockIdx.y, nt = blockIdx.x;

  const int rl = lane >> 2;          // 0..15
  const int kc = (lane & 3) * 8;

  const short* Ag0 = A + (size_t)(mt * 128 + w * 32 + rl) * lda + kc;
  const short* Ag1 = Ag0 + (size_t)16 * lda;
  int rb0 = nt * 128 + w * 32 + rl;      if (rb0 > N - 1) rb0 = N - 1;
  int rb1 = nt * 128 + w * 32 + 16 + rl; if (rb1 > N - 1) rb1 = N - 1;
  const short* Bg0 = B + (size_t)rb0 * ldb + kc;
  const short* Bg1 = B + (size_t)rb1 * ldb + kc;
  short* as0 = &As[(w * 32) * 32];
  short* as1 = &As[(w * 32 + 16) * 32];
  short* bs0 = &Bs[(w * 32) * 32];
  short* bs1 = &Bs[(w * 32 + 16) * 32];

  f32x4 acc[4][4];
#pragma unroll
  for (int ms = 0; ms < 4; ++ms)
#pragma unroll
    for (int ns = 0; ns < 4; ++ns) acc[ms][ns] = (f32x4){0.f, 0.f, 0.f, 0.f};

  const int nkt = K >> 5;
  for (int kt = 0; kt < nkt; ++kt) {
    __syncthreads();
    gload16(Ag0, as0);
    gload16(Ag1, as1);
    gload16(Bg0, bs0);
    gload16(Bg1, bs1);
    Ag0 += 32; Ag1 += 32; Bg0 += 32; Bg1 += 32;
    __syncthreads();
    bf16x8 af[4], bfr[4];
#pragma unroll
    for (int ms = 0; ms < 4; ++ms)
      af[ms] = *(const bf16x8*)&As[(mh * 64 + ms * 16 + c) * 32 + q4 * 8];
#pragma unroll
    for (int ns = 0; ns < 4; ++ns)
      bfr[ns] = *(const bf16x8*)&Bs[(nh * 64 + ns * 16 + c) * 32 + q4 * 8];
#pragma unroll
    for (int ms = 0; ms < 4; ++ms)
#pragma unroll
      for (int ns = 0; ns < 4; ++ns)
        acc[ms][ns] = mfma16(af[ms], bfr[ns], acc[ms][ns]);
  }

#pragma unroll
  for (int ms = 0; ms < 4; ++ms) {
#pragma unroll
    for (int ns = 0; ns < 4; ++ns) {
      const int n = nt * 128 + nh * 64 + ns * 16 + c;
      if (MODE == 0) {
        float bsv = (n < N) ? bias[n] : 0.f;
        float* Co = (float*)Cout;
#pragma unroll
        for (int r = 0; r < 4; ++r) {
          int m = mt * 128 + mh * 64 + ms * 16 + q4 * 4 + r;
          if (n < N) Co[(size_t)m * ldc + n] = acc[ms][ns][r] + bsv;
        }
      } else if (MODE == 1) {
        short* Co = (short*)Cout;
#pragma unroll
        for (int r = 0; r < 4; ++r) {
          int m = mt * 128 + mh * 64 + ms * 16 + q4 * 4 + r;
          if (n < N) Co[(size_t)m * ldc + colofs + n] = f2bs(acc[ms][ns][r]);
        }
      } else {
        float bsv = bias[n];
        int which = n >> 10;
        int h = (n >> 6) & 15;
        int hd = n & 63;
        short* dst = which == 0 ? qo : which == 1 ? ko : vo;
#pragma unroll
        for (int r = 0; r < 4; ++r) {
          int m = mt * 128 + mh * 64 + ms * 16 + q4 * 4 + r;
          int bb = m >> 12, s = m & 4095;
          dst[(size_t)((bb * 16 + h) * 4096 + s) * 64 + hd] = f2bs(acc[ms][ns][r] + bsv);
        }
      }
    }
  }
}

// ---------------- RoPE on Q,K in (B,H,S,HD); Q also scaled by 1/8 ------------
__global__ void rope_k(short* __restrict__ Qb, short* __restrict__ Kb,
                       const float* __restrict__ cf, const float* __restrict__ sf)
{
  unsigned idx = blockIdx.x * 256u + threadIdx.x;   // total 8388608
  const unsigned half = 4194304u;                   // 32*4096*32
  bool isQ = idx < half;
  short* P = isQ ? Qb : Kb;
  unsigned r = idx & (half - 1u);
  unsigned bh = r >> 17;
  unsigned s = (r >> 5) & 4095u;
  unsigned i = r & 31u;
  size_t base = ((size_t)bh * 4096 + s) * 64 + 2u * i;
  unsigned pv = *(const unsigned*)&P[base];
  float e = bs2f((short)(pv & 0xFFFFu));
  float o = bs2f((short)(pv >> 16));
  float cc = cf[s * 32u + i], ss = sf[s * 32u + i];
  float re = e * cc - o * ss;
  float im = e * ss + o * cc;
  if (isQ) { re *= 0.125f; im *= 0.125f; }
  unsigned out = (unsigned)(unsigned short)f2bs(re) |
                 ((unsigned)(unsigned short)f2bs(im) << 16);
  *(unsigned*)&P[base] = out;
}

// ---------------- V transpose: (B,H,S,HD) -> (B,H,HD,S) ----------------------
__global__ __launch_bounds__(256) void vtrans_k(const short* __restrict__ Vb,
                                                short* __restrict__ Vt)
{
  __shared__ short T[64 * 72];
  const int st = blockIdx.x, bh = blockIdx.y;
  const int tid = threadIdx.x;
  const short* src = Vb + ((size_t)bh * 4096 + st * 64) * 64;
#pragma unroll
  for (int i2 = 0; i2 < 2; ++i2) {
    int ch = tid + i2 * 256;
    int r = ch >> 3, kk = (ch & 7) * 8;
    *(int4*)&T[r * 72 + kk] = *(const int4*)&src[r * 64 + kk];
  }
  __syncthreads();
#pragma unroll
  for (int i2 = 0; i2 < 2; ++i2) {
    int ch = tid + i2 * 256;
    int hd = ch & 63, s0 = (ch >> 6) * 8;
    alignas(16) short v[8];
#pragma unroll
    for (int j = 0; j < 8; ++j) v[j] = T[(s0 + j) * 72 + hd];
    *(int4*)&Vt[((size_t)bh * 64 + hd) * 4096 + st * 64 + s0] = *(const int4*)v;
  }
}

// ---------------- Flash attention (causal), BM=BN=64, HD=64 ------------------
// Q pre-scaled by 1/8. Writes O (bf16) into Oaug rows (b*4096+s), cols h*64+hd.
__global__ __launch_bounds__(256) void flash_k(
    const short* __restrict__ Qb, const short* __restrict__ Kb,
    const short* __restrict__ Vt, short* __restrict__ Oaug)
{
  __shared__ short Ks[64 * 72];
  __shared__ short Vs[64 * 72];
  __shared__ short QP[64 * 72];
  const int bh = blockIdx.y;
  const int qt = (int)gridDim.x - 1 - (int)blockIdx.x;   // heavy blocks first
  const int tid = threadIdx.x;
  const int w = tid >> 6, lane = tid & 63;
  const int q4 = lane >> 4, c = lane & 15;

  const short* Qg = Qb + ((size_t)bh * 4096 + qt * 64) * 64;
  const short* Kg = Kb + (size_t)bh * 4096 * 64;
  const short* Vg = Vt + (size_t)bh * 64 * 4096;

#pragma unroll
  for (int i2 = 0; i2 < 2; ++i2) {
    int ch = tid + i2 * 256;
    int r = ch >> 3, kk = (ch & 7) * 8;
    *(int4*)&QP[r * 72 + kk] = *(const int4*)&Qg[r * 64 + kk];
  }
  __syncthreads();
  bf16x8 qf0 = *(const bf16x8*)&QP[(w * 16 + c) * 72 + q4 * 8];
  bf16x8 qf1 = *(const bf16x8*)&QP[(w * 16 + c) * 72 + 32 + q4 * 8];
  // QP rows [16w,16w+16) are wave-private from here on (P buffer reuse).

  f32x4 oacc[4];
  float m_i[4], l_i[4];
#pragma unroll
  for (int i = 0; i < 4; ++i) {
    oacc[i] = (f32x4){0.f, 0.f, 0.f, 0.f};
    m_i[i] = -1e30f; l_i[i] = 0.f;
  }

  for (int kt = 0; kt <= qt; ++kt) {
    __syncthreads();
#pragma unroll
    for (int i2 = 0; i2 < 2; ++i2) {
      int ch = tid + i2 * 256;
      int r = ch >> 3, kk = (ch & 7) * 8;
      int4 kv = *(const int4*)&Kg[((size_t)kt * 64 + r) * 64 + kk];
      int4 vv = *(const int4*)&Vg[(size_t)r * 4096 + kt * 64 + kk];
      *(int4*)&Ks[r * 72 + kk] = kv;
      *(int4*)&Vs[r * 72 + kk] = vv;
    }
    __syncthreads();

    f32x4 sacc[4];
#pragma unroll
    for (int ns = 0; ns < 4; ++ns) {
      sacc[ns] = (f32x4){0.f, 0.f, 0.f, 0.f};
      bf16x8 kf0 = *(const bf16x8*)&Ks[(ns * 16 + c) * 72 + q4 * 8];
      bf16x8 kf1 = *(const bf16x8*)&Ks[(ns * 16 + c) * 72 + 32 + q4 * 8];
      sacc[ns] = mfma16(qf0, kf0, sacc[ns]);
      sacc[ns] = mfma16(qf1, kf1, sacc[ns]);
    }
    if (kt == qt) {
#pragma unroll
      for (int ns = 0; ns < 4; ++ns)
#pragma unroll
        for (int r = 0; r < 4; ++r)
          if (ns * 16 + c > w * 16 + q4 * 4 + r) sacc[ns][r] = -1e30f;
    }
    float mx[4], al[4], sm[4];
#pragma unroll
    for (int r = 0; r < 4; ++r)
      mx[r] = fmaxf(fmaxf(sacc[0][r], sacc[1][r]), fmaxf(sacc[2][r], sacc[3][r]));
#pragma unroll
    for (int d = 1; d < 16; d <<= 1)
#pragma unroll
      for (int r = 0; r < 4; ++r)
        mx[r] = fmaxf(mx[r], __shfl_xor(mx[r], d));
#pragma unroll
    for (int r = 0; r < 4; ++r) {
      float mn = fmaxf(m_i[r], mx[r]);
      al[r] = __expf(m_i[r] - mn);
      m_i[r] = mn;
    }
#pragma unroll
    for (int ns = 0; ns < 4; ++ns)
#pragma unroll
      for (int r = 0; r < 4; ++r)
        sacc[ns][r] = __expf(sacc[ns][r] - m_i[r]);
#pragma unroll
    for (int r = 0; r < 4; ++r)
      sm[r] = (sacc[0][r] + sacc[1][r]) + (sacc[2][r] + sacc[3][r]);
#pragma unroll
    for (int d = 1; d < 16; d <<= 1)
#pragma unroll
      for (int r = 0; r < 4; ++r)
        sm[r] += __shfl_xor(sm[r], d);
#pragma unroll
    for (int r = 0; r < 4; ++r)
      l_i[r] = l_i[r] * al[r] + sm[r];
#pragma unroll
    for (int nc = 0; nc < 4; ++nc)
#pragma unroll
      for (int r = 0; r < 4; ++r)
        oacc[nc][r] *= al[r];
    // P -> LDS (wave-private rows), then read back as A-fragments
#pragma unroll
    for (int ns = 0; ns < 4; ++ns)
#pragma unroll
      for (int r = 0; r < 4; ++r)
        QP[(w * 16 + q4 * 4 + r) * 72 + ns * 16 + c] = f2bs(sacc[ns][r]);

    bf16x8 pf0 = *(const bf16x8*)&QP[(w * 16 + c) * 72 + q4 * 8];
    bf16x8 pf1 = *(const bf16x8*)&QP[(w * 16 + c) * 72 + 32 + q4 * 8];
#pragma unroll
    for (int nc = 0; nc < 4; ++nc) {
      bf16x8 vf0 = *(const bf16x8*)&Vs[(nc * 16 + c) * 72 + q4 * 8];
      bf16x8 vf1 = *(const bf16x8*)&Vs[(nc * 16 + c) * 72 + 32 + q4 * 8];
      oacc[nc] = mfma16(pf0, vf0, oacc[nc]);
      oacc[nc] = mfma16(pf1, vf1, oacc[nc]);
    }
  }

#pragma unroll
  for (int r = 0; r < 4; ++r) l_i[r] = 1.f / l_i[r];
#pragma unroll
  for (int nc = 0; nc < 4; ++nc)
#pragma unroll
    for (int r = 0; r < 4; ++r)
      QP[(w * 16 + q4 * 4 + r) * 72 + nc * 16 + c] = f2bs(oacc[nc][r] * l_i[r]);
  __syncthreads();
  const int b = bh >> 4, h = bh & 15;
#pragma unroll
  for (int i2 = 0; i2 < 2; ++i2) {
    int ch = tid + i2 * 256;
    int r = ch >> 3, kk = (ch & 7) * 8;
    size_t row = (size_t)b * 4096 + qt * 64 + r;
    *(int4*)&Oaug[row * KAUG + h * 64 + kk] = *(const int4*)&QP[r * 72 + kk];
  }
}

// ---------------- host launch ------------------------------------------------
extern "C" void kernel_launch(void* const* d_in, const int* in_sizes, int n_in,
                              void* d_out, int out_size, void* d_ws, size_t ws_size,
                              hipStream_t stream) {
  const float* x   = (const float*)d_in[0];
  const float* fc  = (const float*)d_in[1];
  const float* fs  = (const float*)d_in[2];
  // d_in[3] = mask (causal, reimplemented analytically)
  const float* wq  = (const float*)d_in[4];
  const float* wqb = (const float*)d_in[5];
  const float* wk  = (const float*)d_in[6];
  const float* wv  = (const float*)d_in[7];
  const float* wo  = (const float*)d_in[8];
  const float* wob = (const float*)d_in[9];
  const float* lq1 = (const float*)d_in[10];
  const float* lq2 = (const float*)d_in[11];
  const float* lk1 = (const float*)d_in[12];
  const float* lk2 = (const float*)d_in[13];
  const float* lv1 = (const float*)d_in[14];
  const float* lv2 = (const float*)d_in[15];
  const float* lo1 = (const float*)d_in[16];
  const float* lo2 = (const float*)d_in[17];

  char* ws = (char*)d_ws;
  const size_t OFF_XAUG  = 0;                          // 8192*1088*2 = 17825792
  const size_t OFF_XOAUG = 17825792;                   // 17825792
  const size_t OFF_WQKV  = 35651584;                   // 3072*1088*2 = 6684672
  const size_t OFF_WOAUG = 42336256;                   // 1024*1088*2 = 2228224
  const size_t OFF_L1CAT = 44564480;                   // 64*1024*2 = 131072
  const size_t OFF_BIASC = 44695552;                   // 3072*4 = 12288
  const size_t OFF_QB    = 44707840;                   // 16777216
  const size_t OFF_KB    = 61485056;                   // 16777216
  const size_t OFF_VB    = 78262272;                   // 16777216
  const size_t OFF_VT    = 95039488;                   // 16777216 -> 111816704 total

  short* xaug  = (short*)(ws + OFF_XAUG);
  short* xoaug = (short*)(ws + OFF_XOAUG);
  short* wqkv  = (short*)(ws + OFF_WQKV);
  short* woaug = (short*)(ws + OFF_WOAUG);
  short* l1cat = (short*)(ws + OFF_L1CAT);
  float* biasc = (float*)(ws + OFF_BIASC);
  short* qb    = (short*)(ws + OFF_QB);
  short* kb    = (short*)(ws + OFF_KB);
  short* vb    = (short*)(ws + OFF_VB);
  short* vt    = (short*)(ws + OFF_VT);

  // 1. prep (12913664 elems, exactly 50444 blocks)
  prep_k<<<50444, 256, 0, stream>>>(x, wq, wk, wv, wo, wqb,
                                    lq1, lq2, lk1, lk2, lv1, lv2, lo1, lo2,
                                    xaug, wqkv, woaug, l1cat, biasc);
  // 2. T_qkv = x @ [lq1;lk1;lv1]^T  -> xaug cols 1024..1071
  gemm_bt<1><<<dim3(1, 64), 256, 0, stream>>>(xaug, KAUG, l1cat, 1024, 48, 1024,
                                              nullptr, xaug, KAUG, 1024,
                                              nullptr, nullptr, nullptr);
  // 3. fused QKV projection (LoRA folded into K-dim) -> (B,H,S,HD) bf16
  gemm_bt<2><<<dim3(24, 64), 256, 0, stream>>>(xaug, KAUG, wqkv, KAUG, 3072, KAUG,
                                               biasc, nullptr, 0, 0, qb, kb, vb);
  // 4. RoPE on Q,K (Q scaled by 1/8)
  rope_k<<<32768, 256, 0, stream>>>(qb, kb, fc, fs);
  // 5. V -> V^T per (b,h)
  vtrans_k<<<dim3(64, 32), 256, 0, stream>>>(vb, vt);
  // 6. flash attention -> xoaug cols 0..1023
  flash_k<<<dim3(64, 32), 256, 0, stream>>>(qb, kb, vt, xoaug);
  // 7. T_o = attn_out @ lo1^T -> xoaug cols 1024..1039
  gemm_bt<1><<<dim3(1, 64), 256, 0, stream>>>(xoaug, KAUG, l1cat + 48 * 1024, 1024,
                                              16, 1024, nullptr, xoaug, KAUG, 1024,
                                              nullptr, nullptr, nullptr);
  // 8. final projection -> d_out (fp32)
  gemm_bt<0><<<dim3(8, 64), 256, 0, stream>>>(xoaug, KAUG, woaug, KAUG, 1024, KAUG,
                                              wob, d_out, 1024, 0,
                                              nullptr, nullptr, nullptr);
}

// Round 3
// 588.952 us; speedup vs baseline: 1.2585x; 1.2585x over previous
//
#include <hip/hip_runtime.h>
#include <hip/hip_bf16.h>
#include <stdint.h>

// Problem constants
#define S_DIM 4096
#define D_DIM 1024
#define KAUG  1088          // 1024 + 64 (LoRA-augmented K)
#define M_ROWS 8192         // B*S

typedef short bf16x8 __attribute__((ext_vector_type(8)));
typedef float f32x4  __attribute__((ext_vector_type(4)));

__device__ __forceinline__ f32x4 mfma16(bf16x8 a, bf16x8 b, f32x4 c) {
  return __builtin_amdgcn_mfma_f32_16x16x32_bf16(a, b, c, 0, 0, 0);
}
__device__ __forceinline__ short f2bs(float f) {
  __hip_bfloat16 h = __float2bfloat16(f);
  return *reinterpret_cast<short*>(&h);
}
__device__ __forceinline__ float bs2f(short s) {
  __hip_bfloat16 h;
  *reinterpret_cast<short*>(&h) = s;
  return __bfloat162float(h);
}
__device__ __forceinline__ void gload16(const void* g, void* l) {
  __builtin_amdgcn_global_load_lds(
      (const __attribute__((address_space(1))) unsigned int*)g,
      (__attribute__((address_space(3))) unsigned int*)l, 16, 0, 0);
}

// ---------------- prep: casts + augmented operand construction ----------------
__global__ void prep_k(const float* __restrict__ x,
                       const float* __restrict__ wq, const float* __restrict__ wk,
                       const float* __restrict__ wv, const float* __restrict__ wo,
                       const float* __restrict__ wqb,
                       const float* __restrict__ lq1, const float* __restrict__ lq2,
                       const float* __restrict__ lk1, const float* __restrict__ lk2,
                       const float* __restrict__ lv1, const float* __restrict__ lv2,
                       const float* __restrict__ lo1, const float* __restrict__ lo2,
                       short* __restrict__ xaug, short* __restrict__ wqkv,
                       short* __restrict__ woaug, short* __restrict__ l1cat,
                       float* __restrict__ biasc)
{
  unsigned i = blockIdx.x * 256u + threadIdx.x;
  if (i < 8388608u) {   // R1: x -> bf16 into xaug cols 0..1023
    unsigned m = i >> 10, k = i & 1023u;
    xaug[(size_t)m * KAUG + k] = f2bs(x[i]);
    return;
  }
  i -= 8388608u;
  if (i < 3342336u) {   // R2: wqkv_aug (3072 x 1088)
    unsigned n = i / 1088u, k = i - n * 1088u;
    float v;
    if (k < 1024u) {
      v = (n < 1024u) ? wq[n * 1024u + k]
        : (n < 2048u) ? wk[(n - 1024u) * 1024u + k]
                      : wv[(n - 2048u) * 1024u + k];
    } else {
      unsigned r = k - 1024u, blk = r >> 4, which = n >> 10;
      if (blk == which) {
        const float* l2 = which == 0 ? lq2 : which == 1 ? lk2 : lv2;
        v = l2[(n & 1023u) * 16u + (r & 15u)];
      } else v = 0.f;
    }
    wqkv[i] = f2bs(v);
    return;
  }
  i -= 3342336u;
  if (i < 1114112u) {   // R3: wo_aug (1024 x 1088)
    unsigned n = i / 1088u, k = i - n * 1088u;
    float v = (k < 1024u) ? wo[n * 1024u + k]
            : (k < 1040u) ? lo2[n * 16u + (k - 1024u)] : 0.f;
    woaug[i] = f2bs(v);
    return;
  }
  i -= 1114112u;
  if (i < 65536u) {     // R4: l1cat (64 x 1024)
    unsigned r = i >> 10, k = i & 1023u;
    const float* src = r < 16u ? lq1 : r < 32u ? lk1 : r < 48u ? lv1 : lo1;
    l1cat[i] = f2bs(src[(r & 15u) * 1024u + k]);
    return;
  }
  i -= 65536u;
  if (i < 3072u) {      // R5: bias_cat
    biasc[i] = (i < 1024u) ? wqb[i] : 0.f;
  }
}

// ---------------- GEMM: C[m,n] = sum_k A[m,k]*B[n,k]  (B^T layout) -----------
template<int MODE>
__global__ __launch_bounds__(256) void gemm_bt(
    const short* __restrict__ A, int lda,
    const short* __restrict__ B, int ldb,
    int N, int K,
    const float* __restrict__ bias,
    void* __restrict__ Cout, int ldc, int colofs,
    short* __restrict__ qo, short* __restrict__ ko, short* __restrict__ vo)
{
  __shared__ short As[128 * 32];
  __shared__ short Bs[128 * 32];
  const int tid = threadIdx.x;
  const int w = tid >> 6, lane = tid & 63;
  const int q4 = lane >> 4, c = lane & 15;
  const int mh = w >> 1, nh = w & 1;
  const int mt = blockIdx.y, nt = blockIdx.x;

  const int rl = lane >> 2;          // 0..15
  const int kc = (lane & 3) * 8;

  const short* Ag0 = A + (size_t)(mt * 128 + w * 32 + rl) * lda + kc;
  const short* Ag1 = Ag0 + (size_t)16 * lda;
  int rb0 = nt * 128 + w * 32 + rl;      if (rb0 > N - 1) rb0 = N - 1;
  int rb1 = nt * 128 + w * 32 + 16 + rl; if (rb1 > N - 1) rb1 = N - 1;
  const short* Bg0 = B + (size_t)rb0 * ldb + kc;
  const short* Bg1 = B + (size_t)rb1 * ldb + kc;
  short* as0 = &As[(w * 32) * 32];
  short* as1 = &As[(w * 32 + 16) * 32];
  short* bs0 = &Bs[(w * 32) * 32];
  short* bs1 = &Bs[(w * 32 + 16) * 32];

  f32x4 acc[4][4];
#pragma unroll
  for (int ms = 0; ms < 4; ++ms)
#pragma unroll
    for (int ns = 0; ns < 4; ++ns) acc[ms][ns] = (f32x4){0.f, 0.f, 0.f, 0.f};

  const int nkt = K >> 5;
  for (int kt = 0; kt < nkt; ++kt) {
    __syncthreads();
    gload16(Ag0, as0);
    gload16(Ag1, as1);
    gload16(Bg0, bs0);
    gload16(Bg1, bs1);
    Ag0 += 32; Ag1 += 32; Bg0 += 32; Bg1 += 32;
    __syncthreads();
    bf16x8 af[4], bfr[4];
#pragma unroll
    for (int ms = 0; ms < 4; ++ms)
      af[ms] = *(const bf16x8*)&As[(mh * 64 + ms * 16 + c) * 32 + q4 * 8];
#pragma unroll
    for (int ns = 0; ns < 4; ++ns)
      bfr[ns] = *(const bf16x8*)&Bs[(nh * 64 + ns * 16 + c) * 32 + q4 * 8];
#pragma unroll
    for (int ms = 0; ms < 4; ++ms)
#pragma unroll
      for (int ns = 0; ns < 4; ++ns)
        acc[ms][ns] = mfma16(af[ms], bfr[ns], acc[ms][ns]);
  }

#pragma unroll
  for (int ms = 0; ms < 4; ++ms) {
#pragma unroll
    for (int ns = 0; ns < 4; ++ns) {
      const int n = nt * 128 + nh * 64 + ns * 16 + c;
      if (MODE == 0) {
        float bsv = (n < N) ? bias[n] : 0.f;
        float* Co = (float*)Cout;
#pragma unroll
        for (int r = 0; r < 4; ++r) {
          int m = mt * 128 + mh * 64 + ms * 16 + q4 * 4 + r;
          if (n < N) Co[(size_t)m * ldc + n] = acc[ms][ns][r] + bsv;
        }
      } else if (MODE == 1) {
        short* Co = (short*)Cout;
#pragma unroll
        for (int r = 0; r < 4; ++r) {
          int m = mt * 128 + mh * 64 + ms * 16 + q4 * 4 + r;
          if (n < N) Co[(size_t)m * ldc + colofs + n] = f2bs(acc[ms][ns][r]);
        }
      } else {
        float bsv = bias[n];
        int which = n >> 10;
        int h = (n >> 6) & 15;
        int hd = n & 63;
        short* dst = which == 0 ? qo : which == 1 ? ko : vo;
#pragma unroll
        for (int r = 0; r < 4; ++r) {
          int m = mt * 128 + mh * 64 + ms * 16 + q4 * 4 + r;
          int bb = m >> 12, s = m & 4095;
          dst[(size_t)((bb * 16 + h) * 4096 + s) * 64 + hd] = f2bs(acc[ms][ns][r] + bsv);
        }
      }
    }
  }
}

// ---------------- RoPE on Q,K in (B,H,S,HD) ---------------------------------
// Q scaled by (1/8)*log2(e) so flash can use exp2 directly.
__global__ void rope_k(short* __restrict__ Qb, short* __restrict__ Kb,
                       const float* __restrict__ cf, const float* __restrict__ sf)
{
  unsigned idx = blockIdx.x * 256u + threadIdx.x;   // total 8388608
  const unsigned half = 4194304u;                   // 32*4096*32
  bool isQ = idx < half;
  short* P = isQ ? Qb : Kb;
  unsigned r = idx & (half - 1u);
  unsigned bh = r >> 17;
  unsigned s = (r >> 5) & 4095u;
  unsigned i = r & 31u;
  size_t base = ((size_t)bh * 4096 + s) * 64 + 2u * i;
  unsigned pv = *(const unsigned*)&P[base];
  float e = bs2f((short)(pv & 0xFFFFu));
  float o = bs2f((short)(pv >> 16));
  float cc = cf[s * 32u + i], ss = sf[s * 32u + i];
  float re = e * cc - o * ss;
  float im = e * ss + o * cc;
  if (isQ) { re *= 0.18033688011112042f; im *= 0.18033688011112042f; }  // 0.125*log2e
  unsigned out = (unsigned)(unsigned short)f2bs(re) |
                 ((unsigned)(unsigned short)f2bs(im) << 16);
  *(unsigned*)&P[base] = out;
}

// ---------------- V transpose: (B,H,S,HD) -> (B,H,HD,S) ----------------------
__global__ __launch_bounds__(256) void vtrans_k(const short* __restrict__ Vb,
                                                short* __restrict__ Vt)
{
  __shared__ short T[64 * 72];
  const int st = blockIdx.x, bh = blockIdx.y;
  const int tid = threadIdx.x;
  const short* src = Vb + ((size_t)bh * 4096 + st * 64) * 64;
#pragma unroll
  for (int i2 = 0; i2 < 2; ++i2) {
    int ch = tid + i2 * 256;
    int r = ch >> 3, kk = (ch & 7) * 8;
    *(int4*)&T[r * 72 + kk] = *(const int4*)&src[r * 64 + kk];
  }
  __syncthreads();
#pragma unroll
  for (int i2 = 0; i2 < 2; ++i2) {
    int ch = tid + i2 * 256;
    int hd = ch & 63, s0 = (ch >> 6) * 8;
    alignas(16) short v[8];
#pragma unroll
    for (int j = 0; j < 8; ++j) v[j] = T[(s0 + j) * 72 + hd];
    *(int4*)&Vt[((size_t)bh * 64 + hd) * 4096 + st * 64 + s0] = *(const int4*)v;
  }
}

// ---------------- Flash attention v2 (S^T structure, causal) -----------------
// S^T = K·Q^T  (softmax row axis = lane axis -> per-lane m/l state, 2 shfls)
// O^T = V^T·P^T, all staging via swizzled unpadded LDS + global_load_lds,
// double-buffered K/V, one barrier per KV tile.
// LDS map (shorts): Kbuf0 @0, Kbuf1 @4096, Vbuf0 @8192, Vbuf1 @12288,
//                   PL @16384 (4096: Q staging, then P, then O) = 40960 B total.
__global__ __launch_bounds__(256, 4) void flash_k(
    const short* __restrict__ Qb, const short* __restrict__ Kb,
    const short* __restrict__ Vt, short* __restrict__ Oaug)
{
  __shared__ short lds[20480];
  short* const PL = &lds[16384];

  const int bh = blockIdx.y;
  const int qt = (int)gridDim.x - 1 - (int)blockIdx.x;   // heavy blocks first
  const int tid = threadIdx.x;
  const int w = tid >> 6, lane = tid & 63;
  const int q4 = lane >> 4, c = lane & 15;

  const short* Qg = Qb + ((size_t)bh * 4096 + qt * 64) * 64;
  const short* Kg = Kb + (size_t)bh * 4096 * 64;
  const short* Vg = Vt + (size_t)bh * 64 * 4096;

  // ---- staging source offsets (shorts), XOR-swizzled chunk layout ----
  const int l8 = lane >> 3, l7 = lane & 7;
  const int sw = (l7 ^ l8) * 8;
  const int G0 = w * 2, G1 = w * 2 + 1;
  const int koff0 = (G0 * 8 + l8) * 64 + sw;       // K: row-major rows
  const int koff1 = (G1 * 8 + l8) * 64 + sw;
  const int voff0 = (G0 * 8 + l8) * 4096 + sw;     // V^T: hd-major rows
  const int voff1 = (G1 * 8 + l8) * 4096 + sw;

  // ---- fragment read offsets (shorts) ----
  const int c7 = c & 7;
  const int chA0 = ((q4) ^ c7) * 8;                // k-chunk t=0
  const int chA1 = ((4 + q4) ^ c7) * 8;            // k-chunk t=1
  const int rowc = c * 64;                         // row = (blk*16 + c)
  const int rowq = (w * 16 + c) * 64;              // Q/P/O row for this wave
  // P/O packed-write offset: chunk g = ns*2 + (q4>>1), sub = (q4&1)*4
  const int pw_base = (w * 16 + c) * 64 + (q4 & 1) * 4;
  const int pw_g = q4 >> 1;

  // ---- prologue: stage Q -> PL, K/V tile 0 -> buf0 ----
  gload16(Qg + koff0, &lds[16384 + G0 * 512]);
  gload16(Qg + koff1, &lds[16384 + G1 * 512]);
  gload16(Kg + koff0, &lds[G0 * 512]);
  gload16(Kg + koff1, &lds[G1 * 512]);
  gload16(Vg + voff0, &lds[8192 + G0 * 512]);
  gload16(Vg + voff1, &lds[8192 + G1 * 512]);
  __syncthreads();

  bf16x8 qf0 = *(const bf16x8*)(PL + rowq + chA0);
  bf16x8 qf1 = *(const bf16x8*)(PL + rowq + chA1);

  f32x4 oacc[4];
#pragma unroll
  for (int i = 0; i < 4; ++i) oacc[i] = (f32x4){0.f, 0.f, 0.f, 0.f};
  float m_i = -1e30f, l_i = 0.f;

  for (int kt = 0; kt <= qt; ++kt) {
    const int cur = (kt & 1) * 4096;
    const short* Kc = &lds[cur];
    const short* Vc = &lds[8192 + cur];
    if (kt < qt) {                       // prefetch next tile (overlaps compute)
      const int nxt = ((kt + 1) & 1) * 4096;
      short* Kn = &lds[nxt];
      short* Vn = &lds[8192 + nxt];
      const short* ks = Kg + (size_t)(kt + 1) * 4096;
      const short* vs = Vg + (size_t)(kt + 1) * 64;
      gload16(ks + koff0, Kn + G0 * 512);
      gload16(ks + koff1, Kn + G1 * 512);
      gload16(vs + voff0, Vn + G0 * 512);
      gload16(vs + voff1, Vn + G1 * 512);
    }

    // S^T = K·Q^T : st[ns][r] = S(k = ns*16+q4*4+r, m = c)
    f32x4 st[4];
#pragma unroll
    for (int ns = 0; ns < 4; ++ns) {
      bf16x8 kf0 = *(const bf16x8*)(Kc + ns * 1024 + rowc + chA0);
      bf16x8 kf1 = *(const bf16x8*)(Kc + ns * 1024 + rowc + chA1);
      st[ns] = mfma16(kf0, qf0, (f32x4){0.f, 0.f, 0.f, 0.f});
      st[ns] = mfma16(kf1, qf1, st[ns]);
    }
    if (kt == qt) {                      // diagonal-block causal mask
#pragma unroll
      for (int ns = 0; ns < 4; ++ns)
#pragma unroll
        for (int r = 0; r < 4; ++r)
          if (ns * 16 + q4 * 4 + r > w * 16 + c) st[ns][r] = -1e30f;
    }

    // online softmax, per-lane state (row = c)
    float vm = st[0][0];
#pragma unroll
    for (int ns = 0; ns < 4; ++ns)
#pragma unroll
      for (int r = 0; r < 4; ++r) vm = fmaxf(vm, st[ns][r]);
    vm = fmaxf(vm, __shfl_xor(vm, 16));
    vm = fmaxf(vm, __shfl_xor(vm, 32));
    float mn = fmaxf(m_i, vm);
    float al = exp2f(m_i - mn);
    m_i = mn;

    float ps[4][4];
    float sum = 0.f;
#pragma unroll
    for (int ns = 0; ns < 4; ++ns)
#pragma unroll
      for (int r = 0; r < 4; ++r) {
        ps[ns][r] = exp2f(st[ns][r] - mn);
        sum += ps[ns][r];
      }
    sum += __shfl_xor(sum, 16);
    sum += __shfl_xor(sum, 32);
    l_i = l_i * al + sum;
#pragma unroll
    for (int nc = 0; nc < 4; ++nc)
#pragma unroll
      for (int r = 0; r < 4; ++r) oacc[nc][r] *= al;

    // P^T -> PL (packed b64, swizzled, wave-private rows)
#pragma unroll
    for (int ns = 0; ns < 4; ++ns) {
      short4 pk;
      pk.x = f2bs(ps[ns][0]); pk.y = f2bs(ps[ns][1]);
      pk.z = f2bs(ps[ns][2]); pk.w = f2bs(ps[ns][3]);
      *(short4*)(PL + pw_base + (((ns * 2 + pw_g) ^ c7) * 8)) = pk;
    }
    bf16x8 pf0 = *(const bf16x8*)(PL + rowq + chA0);
    bf16x8 pf1 = *(const bf16x8*)(PL + rowq + chA1);

    // O^T += V^T·P^T
#pragma unroll
    for (int nc = 0; nc < 4; ++nc) {
      bf16x8 vf0 = *(const bf16x8*)(Vc + nc * 1024 + rowc + chA0);
      bf16x8 vf1 = *(const bf16x8*)(Vc + nc * 1024 + rowc + chA1);
      oacc[nc] = mfma16(vf0, pf0, oacc[nc]);
      oacc[nc] = mfma16(vf1, pf1, oacc[nc]);
    }
    __syncthreads();                     // drains prefetch; frees cur buffers
  }

  // epilogue: normalize, O^T -> PL (transpose via LDS), then coalesced store
  float linv = 1.f / l_i;
#pragma unroll
  for (int nc = 0; nc < 4; ++nc) {
    short4 ok;
    ok.x = f2bs(oacc[nc][0] * linv); ok.y = f2bs(oacc[nc][1] * linv);
    ok.z = f2bs(oacc[nc][2] * linv); ok.w = f2bs(oacc[nc][3] * linv);
    *(short4*)(PL + pw_base + (((nc * 2 + pw_g) ^ c7) * 8)) = ok;
  }
  __syncthreads();
  const int b = bh >> 4, h = bh & 15;
#pragma unroll
  for (int i2 = 0; i2 < 2; ++i2) {
    int ch = tid + i2 * 256;
    int r = ch >> 3, g = ch & 7;
    size_t row = (size_t)b * 4096 + qt * 64 + r;
    *(int4*)&Oaug[row * KAUG + h * 64 + g * 8] =
        *(const int4*)(PL + r * 64 + ((g ^ (r & 7)) * 8));
  }
}

// ---------------- host launch ------------------------------------------------
extern "C" void kernel_launch(void* const* d_in, const int* in_sizes, int n_in,
                              void* d_out, int out_size, void* d_ws, size_t ws_size,
                              hipStream_t stream) {
  const float* x   = (const float*)d_in[0];
  const float* fc  = (const float*)d_in[1];
  const float* fs  = (const float*)d_in[2];
  // d_in[3] = mask (causal, reimplemented analytically)
  const float* wq  = (const float*)d_in[4];
  const float* wqb = (const float*)d_in[5];
  const float* wk  = (const float*)d_in[6];
  const float* wv  = (const float*)d_in[7];
  const float* wo  = (const float*)d_in[8];
  const float* wob = (const float*)d_in[9];
  const float* lq1 = (const float*)d_in[10];
  const float* lq2 = (const float*)d_in[11];
  const float* lk1 = (const float*)d_in[12];
  const float* lk2 = (const float*)d_in[13];
  const float* lv1 = (const float*)d_in[14];
  const float* lv2 = (const float*)d_in[15];
  const float* lo1 = (const float*)d_in[16];
  const float* lo2 = (const float*)d_in[17];

  char* ws = (char*)d_ws;
  const size_t OFF_XAUG  = 0;
  const size_t OFF_XOAUG = 17825792;
  const size_t OFF_WQKV  = 35651584;
  const size_t OFF_WOAUG = 42336256;
  const size_t OFF_L1CAT = 44564480;
  const size_t OFF_BIASC = 44695552;
  const size_t OFF_QB    = 44707840;
  const size_t OFF_KB    = 61485056;
  const size_t OFF_VB    = 78262272;
  const size_t OFF_VT    = 95039488;

  short* xaug  = (short*)(ws + OFF_XAUG);
  short* xoaug = (short*)(ws + OFF_XOAUG);
  short* wqkv  = (short*)(ws + OFF_WQKV);
  short* woaug = (short*)(ws + OFF_WOAUG);
  short* l1cat = (short*)(ws + OFF_L1CAT);
  float* biasc = (float*)(ws + OFF_BIASC);
  short* qb    = (short*)(ws + OFF_QB);
  short* kb    = (short*)(ws + OFF_KB);
  short* vb    = (short*)(ws + OFF_VB);
  short* vt    = (short*)(ws + OFF_VT);

  prep_k<<<50444, 256, 0, stream>>>(x, wq, wk, wv, wo, wqb,
                                    lq1, lq2, lk1, lk2, lv1, lv2, lo1, lo2,
                                    xaug, wqkv, woaug, l1cat, biasc);
  gemm_bt<1><<<dim3(1, 64), 256, 0, stream>>>(xaug, KAUG, l1cat, 1024, 48, 1024,
                                              nullptr, xaug, KAUG, 1024,
                                              nullptr, nullptr, nullptr);
  gemm_bt<2><<<dim3(24, 64), 256, 0, stream>>>(xaug, KAUG, wqkv, KAUG, 3072, KAUG,
                                               biasc, nullptr, 0, 0, qb, kb, vb);
  rope_k<<<32768, 256, 0, stream>>>(qb, kb, fc, fs);
  vtrans_k<<<dim3(64, 32), 256, 0, stream>>>(vb, vt);
  flash_k<<<dim3(64, 32), 256, 0, stream>>>(qb, kb, vt, xoaug);
  gemm_bt<1><<<dim3(1, 64), 256, 0, stream>>>(xoaug, KAUG, l1cat + 48 * 1024, 1024,
                                              16, 1024, nullptr, xoaug, KAUG, 1024,
                                              nullptr, nullptr, nullptr);
  gemm_bt<0><<<dim3(8, 64), 256, 0, stream>>>(xoaug, KAUG, woaug, KAUG, 1024, KAUG,
                                              wob, d_out, 1024, 0,
                                              nullptr, nullptr, nullptr);
}

// Round 4
// 495.021 us; speedup vs baseline: 1.4973x; 1.1898x over previous
//
#include <hip/hip_runtime.h>
#include <hip/hip_bf16.h>
#include <stdint.h>

// Problem constants
#define S_DIM 4096
#define D_DIM 1024
#define KAUG  1088          // 1024 + 64 (LoRA-augmented K)
#define M_ROWS 8192         // B*S

typedef short bf16x8 __attribute__((ext_vector_type(8)));
typedef float f32x4  __attribute__((ext_vector_type(4)));

__device__ __forceinline__ f32x4 mfma16(bf16x8 a, bf16x8 b, f32x4 c) {
  return __builtin_amdgcn_mfma_f32_16x16x32_bf16(a, b, c, 0, 0, 0);
}
__device__ __forceinline__ short f2bs(float f) {
  __hip_bfloat16 h = __float2bfloat16(f);
  return *reinterpret_cast<short*>(&h);
}
__device__ __forceinline__ float bs2f(short s) {
  __hip_bfloat16 h;
  *reinterpret_cast<short*>(&h) = s;
  return __bfloat162float(h);
}
__device__ __forceinline__ unsigned pk2bf(float a, float b) {
  __hip_bfloat162 h = __float22bfloat162_rn(float2{a, b});
  return *reinterpret_cast<unsigned*>(&h);
}
__device__ __forceinline__ void gload16(const void* g, void* l) {
  __builtin_amdgcn_global_load_lds(
      (const __attribute__((address_space(1))) unsigned int*)g,
      (__attribute__((address_space(3))) unsigned int*)l, 16, 0, 0);
}

// ---------------- prep: casts + augmented operand construction ----------------
__global__ void prep_k(const float* __restrict__ x,
                       const float* __restrict__ wq, const float* __restrict__ wk,
                       const float* __restrict__ wv, const float* __restrict__ wo,
                       const float* __restrict__ wqb,
                       const float* __restrict__ lq1, const float* __restrict__ lq2,
                       const float* __restrict__ lk1, const float* __restrict__ lk2,
                       const float* __restrict__ lv1, const float* __restrict__ lv2,
                       const float* __restrict__ lo1, const float* __restrict__ lo2,
                       short* __restrict__ xaug, short* __restrict__ wqkv,
                       short* __restrict__ woaug, short* __restrict__ l1cat,
                       float* __restrict__ biasc)
{
  unsigned i = blockIdx.x * 256u + threadIdx.x;
  if (i < 8388608u) {   // R1: x -> bf16 into xaug cols 0..1023
    unsigned m = i >> 10, k = i & 1023u;
    xaug[(size_t)m * KAUG + k] = f2bs(x[i]);
    return;
  }
  i -= 8388608u;
  if (i < 3342336u) {   // R2: wqkv_aug (3072 x 1088)
    unsigned n = i / 1088u, k = i - n * 1088u;
    float v;
    if (k < 1024u) {
      v = (n < 1024u) ? wq[n * 1024u + k]
        : (n < 2048u) ? wk[(n - 1024u) * 1024u + k]
                      : wv[(n - 2048u) * 1024u + k];
    } else {
      unsigned r = k - 1024u, blk = r >> 4, which = n >> 10;
      if (blk == which) {
        const float* l2 = which == 0 ? lq2 : which == 1 ? lk2 : lv2;
        v = l2[(n & 1023u) * 16u + (r & 15u)];
      } else v = 0.f;
    }
    wqkv[i] = f2bs(v);
    return;
  }
  i -= 3342336u;
  if (i < 1114112u) {   // R3: wo_aug (1024 x 1088)
    unsigned n = i / 1088u, k = i - n * 1088u;
    float v = (k < 1024u) ? wo[n * 1024u + k]
            : (k < 1040u) ? lo2[n * 16u + (k - 1024u)] : 0.f;
    woaug[i] = f2bs(v);
    return;
  }
  i -= 1114112u;
  if (i < 65536u) {     // R4: l1cat (64 x 1024)
    unsigned r = i >> 10, k = i & 1023u;
    const float* src = r < 16u ? lq1 : r < 32u ? lk1 : r < 48u ? lv1 : lo1;
    l1cat[i] = f2bs(src[(r & 15u) * 1024u + k]);
    return;
  }
  i -= 65536u;
  if (i < 3072u) {      // R5: bias_cat
    biasc[i] = (i < 1024u) ? wqb[i] : 0.f;
  }
}

// ---------------- GEMM: C[m,n] = sum_k A[m,k]*B[n,k]  (B^T layout) -----------
// MODE 0: fp32 out + bias   MODE 1: bf16 out at [m*ldc+colofs+n]
// MODE 2: QKV scatter: Q,K -> (B,H,S,HD); V -> transposed (B,H,HD,S) packed
template<int MODE>
__global__ __launch_bounds__(256) void gemm_bt(
    const short* __restrict__ A, int lda,
    const short* __restrict__ B, int ldb,
    int N, int K,
    const float* __restrict__ bias,
    void* __restrict__ Cout, int ldc, int colofs,
    short* __restrict__ qo, short* __restrict__ ko, short* __restrict__ vo)
{
  __shared__ short As[128 * 32];
  __shared__ short Bs[128 * 32];
  const int tid = threadIdx.x;
  const int w = tid >> 6, lane = tid & 63;
  const int q4 = lane >> 4, c = lane & 15;
  const int mh = w >> 1, nh = w & 1;
  const int mt = blockIdx.y, nt = blockIdx.x;

  const int rl = lane >> 2;          // 0..15
  const int kc = (lane & 3) * 8;

  const short* Ag0 = A + (size_t)(mt * 128 + w * 32 + rl) * lda + kc;
  const short* Ag1 = Ag0 + (size_t)16 * lda;
  int rb0 = nt * 128 + w * 32 + rl;      if (rb0 > N - 1) rb0 = N - 1;
  int rb1 = nt * 128 + w * 32 + 16 + rl; if (rb1 > N - 1) rb1 = N - 1;
  const short* Bg0 = B + (size_t)rb0 * ldb + kc;
  const short* Bg1 = B + (size_t)rb1 * ldb + kc;
  short* as0 = &As[(w * 32) * 32];
  short* as1 = &As[(w * 32 + 16) * 32];
  short* bs0 = &Bs[(w * 32) * 32];
  short* bs1 = &Bs[(w * 32 + 16) * 32];

  f32x4 acc[4][4];
#pragma unroll
  for (int ms = 0; ms < 4; ++ms)
#pragma unroll
    for (int ns = 0; ns < 4; ++ns) acc[ms][ns] = (f32x4){0.f, 0.f, 0.f, 0.f};

  const int nkt = K >> 5;
  for (int kt = 0; kt < nkt; ++kt) {
    __syncthreads();
    gload16(Ag0, as0);
    gload16(Ag1, as1);
    gload16(Bg0, bs0);
    gload16(Bg1, bs1);
    Ag0 += 32; Ag1 += 32; Bg0 += 32; Bg1 += 32;
    __syncthreads();
    bf16x8 af[4], bfr[4];
#pragma unroll
    for (int ms = 0; ms < 4; ++ms)
      af[ms] = *(const bf16x8*)&As[(mh * 64 + ms * 16 + c) * 32 + q4 * 8];
#pragma unroll
    for (int ns = 0; ns < 4; ++ns)
      bfr[ns] = *(const bf16x8*)&Bs[(nh * 64 + ns * 16 + c) * 32 + q4 * 8];
#pragma unroll
    for (int ms = 0; ms < 4; ++ms)
#pragma unroll
      for (int ns = 0; ns < 4; ++ns)
        acc[ms][ns] = mfma16(af[ms], bfr[ns], acc[ms][ns]);
  }

#pragma unroll
  for (int ms = 0; ms < 4; ++ms) {
#pragma unroll
    for (int ns = 0; ns < 4; ++ns) {
      const int n = nt * 128 + nh * 64 + ns * 16 + c;
      if (MODE == 0) {
        float bsv = (n < N) ? bias[n] : 0.f;
        float* Co = (float*)Cout;
#pragma unroll
        for (int r = 0; r < 4; ++r) {
          int m = mt * 128 + mh * 64 + ms * 16 + q4 * 4 + r;
          if (n < N) Co[(size_t)m * ldc + n] = acc[ms][ns][r] + bsv;
        }
      } else if (MODE == 1) {
        short* Co = (short*)Cout;
#pragma unroll
        for (int r = 0; r < 4; ++r) {
          int m = mt * 128 + mh * 64 + ms * 16 + q4 * 4 + r;
          if (n < N) Co[(size_t)m * ldc + colofs + n] = f2bs(acc[ms][ns][r]);
        }
      } else {
        float bsv = bias[n];
        int which = n >> 10;
        int h = (n >> 6) & 15;
        int hd = n & 63;
        int m0 = mt * 128 + mh * 64 + ms * 16 + q4 * 4;
        int bb = m0 >> 12, s = m0 & 4095;
        if (which < 2) {
          short* dst = which == 0 ? qo : ko;
#pragma unroll
          for (int r = 0; r < 4; ++r)
            dst[(size_t)((bb * 16 + h) * 4096 + s + r) * 64 + hd] =
                f2bs(acc[ms][ns][r] + bsv);
        } else {
          // V: write directly transposed (B,H,HD,S); 4 consecutive s -> short4
          short4 vk;
          vk.x = f2bs(acc[ms][ns][0] + bsv);
          vk.y = f2bs(acc[ms][ns][1] + bsv);
          vk.z = f2bs(acc[ms][ns][2] + bsv);
          vk.w = f2bs(acc[ms][ns][3] + bsv);
          *(short4*)&vo[(((size_t)bb * 16 + h) * 64 + hd) * 4096 + s] = vk;
        }
      }
    }
  }
}

// ---------------- RoPE on Q,K in (B,H,S,HD) ---------------------------------
// Q scaled by (1/8)*log2(e) so flash can use exp2 directly.
__global__ void rope_k(short* __restrict__ Qb, short* __restrict__ Kb,
                       const float* __restrict__ cf, const float* __restrict__ sf)
{
  unsigned idx = blockIdx.x * 256u + threadIdx.x;   // total 8388608
  const unsigned half = 4194304u;                   // 32*4096*32
  bool isQ = idx < half;
  short* P = isQ ? Qb : Kb;
  unsigned r = idx & (half - 1u);
  unsigned bh = r >> 17;
  unsigned s = (r >> 5) & 4095u;
  unsigned i = r & 31u;
  size_t base = ((size_t)bh * 4096 + s) * 64 + 2u * i;
  unsigned pv = *(const unsigned*)&P[base];
  float e = bs2f((short)(pv & 0xFFFFu));
  float o = bs2f((short)(pv >> 16));
  float cc = cf[s * 32u + i], ss = sf[s * 32u + i];
  float re = e * cc - o * ss;
  float im = e * ss + o * cc;
  if (isQ) { re *= 0.18033688011112042f; im *= 0.18033688011112042f; }  // 0.125*log2e
  *(unsigned*)&P[base] = pk2bf(re, im);
}

// ---------------- Flash attention v3 (S^T structure, paired Q-tiles) ---------
// Each block handles qt = 63-bx (heavy) then qt = bx (light): uniform 65
// KV-iterations per block; grid = 1024 blocks = exactly 4/CU resident.
// S^T = K·Q^T (per-lane softmax state), O^T = V^T·P^T.
// LDS map (shorts): Kbuf0 @0, Kbuf1 @4096, Vbuf0 @8192, Vbuf1 @12288,
//                   PL @16384 (Q staging / P / O) = 40960 B total.
__global__ __launch_bounds__(256, 4) void flash_k(
    const short* __restrict__ Qb, const short* __restrict__ Kb,
    const short* __restrict__ Vt, short* __restrict__ Oaug)
{
  __shared__ short lds[20480];
  short* const PL = &lds[16384];

  const int bh = blockIdx.y;
  const int tid = threadIdx.x;
  const int w = tid >> 6, lane = tid & 63;
  const int q4 = lane >> 4, c = lane & 15;

  const short* Kg = Kb + (size_t)bh * 4096 * 64;
  const short* Vg = Vt + (size_t)bh * 64 * 4096;

  // staging source offsets (shorts), XOR-swizzled chunk layout
  const int l8 = lane >> 3, l7 = lane & 7;
  const int sw = (l7 ^ l8) * 8;
  const int G0 = w * 2, G1 = w * 2 + 1;
  const int koff0 = (G0 * 8 + l8) * 64 + sw;       // K/Q: row-major rows
  const int koff1 = (G1 * 8 + l8) * 64 + sw;
  const int voff0 = (G0 * 8 + l8) * 4096 + sw;     // V^T: hd-major rows
  const int voff1 = (G1 * 8 + l8) * 4096 + sw;

  // fragment read offsets (shorts)
  const int c7 = c & 7;
  const int chA0 = ((q4) ^ c7) * 8;                // k-chunk t=0
  const int chA1 = ((4 + q4) ^ c7) * 8;            // k-chunk t=1
  const int rowc = c * 64;                         // row = (blk*16 + c)
  const int rowq = (w * 16 + c) * 64;              // Q/P/O row for this wave
  const int pw_base = (w * 16 + c) * 64 + (q4 & 1) * 4;
  const int pw_g = q4 >> 1;

  const int b = bh >> 4, h = bh & 15;

  for (int half = 0; half < 2; ++half) {
    const int qt = half == 0 ? 63 - (int)blockIdx.x : (int)blockIdx.x;
    const short* Qg = Qb + ((size_t)bh * 4096 + qt * 64) * 64;

    // prologue: stage Q -> PL, K/V tile 0 -> buf0
    gload16(Qg + koff0, &lds[16384 + G0 * 512]);
    gload16(Qg + koff1, &lds[16384 + G1 * 512]);
    gload16(Kg + koff0, &lds[G0 * 512]);
    gload16(Kg + koff1, &lds[G1 * 512]);
    gload16(Vg + voff0, &lds[8192 + G0 * 512]);
    gload16(Vg + voff1, &lds[8192 + G1 * 512]);
    __syncthreads();

    bf16x8 qf0 = *(const bf16x8*)(PL + rowq + chA0);
    bf16x8 qf1 = *(const bf16x8*)(PL + rowq + chA1);

    f32x4 oacc[4];
#pragma unroll
    for (int i = 0; i < 4; ++i) oacc[i] = (f32x4){0.f, 0.f, 0.f, 0.f};
    float m_i = -1e30f, l_i = 0.f;

    for (int kt = 0; kt <= qt; ++kt) {
      const int cur = (kt & 1) * 4096;
      const short* Kc = &lds[cur];
      const short* Vc = &lds[8192 + cur];
      if (kt < qt) {                     // prefetch next tile (overlaps compute)
        const int nxt = ((kt + 1) & 1) * 4096;
        const short* ks = Kg + (size_t)(kt + 1) * 4096;
        const short* vs = Vg + (size_t)(kt + 1) * 64;
        gload16(ks + koff0, &lds[nxt + G0 * 512]);
        gload16(ks + koff1, &lds[nxt + G1 * 512]);
        gload16(vs + voff0, &lds[8192 + nxt + G0 * 512]);
        gload16(vs + voff1, &lds[8192 + nxt + G1 * 512]);
      }

      // S^T = K·Q^T : st[ns][r] = S(k = ns*16+q4*4+r, m = c)
      f32x4 st[4];
#pragma unroll
      for (int ns = 0; ns < 4; ++ns) {
        bf16x8 kf0 = *(const bf16x8*)(Kc + ns * 1024 + rowc + chA0);
        bf16x8 kf1 = *(const bf16x8*)(Kc + ns * 1024 + rowc + chA1);
        st[ns] = mfma16(kf0, qf0, (f32x4){0.f, 0.f, 0.f, 0.f});
        st[ns] = mfma16(kf1, qf1, st[ns]);
      }
      if (kt == qt) {                    // diagonal-block causal mask
#pragma unroll
        for (int ns = 0; ns < 4; ++ns)
#pragma unroll
          for (int r = 0; r < 4; ++r)
            if (ns * 16 + q4 * 4 + r > w * 16 + c) st[ns][r] = -1e30f;
      }

      // online softmax, per-lane state (row = c)
      float vm = st[0][0];
#pragma unroll
      for (int ns = 0; ns < 4; ++ns)
#pragma unroll
        for (int r = 0; r < 4; ++r) vm = fmaxf(vm, st[ns][r]);
      vm = fmaxf(vm, __shfl_xor(vm, 16));
      vm = fmaxf(vm, __shfl_xor(vm, 32));
      float mn = fmaxf(m_i, vm);
      float al = exp2f(m_i - mn);
      m_i = mn;

      float ps[4][4];
      float sum = 0.f;
#pragma unroll
      for (int ns = 0; ns < 4; ++ns)
#pragma unroll
        for (int r = 0; r < 4; ++r) {
          ps[ns][r] = exp2f(st[ns][r] - mn);
          sum += ps[ns][r];
        }
      sum += __shfl_xor(sum, 16);
      sum += __shfl_xor(sum, 32);
      l_i = l_i * al + sum;
#pragma unroll
      for (int nc = 0; nc < 4; ++nc) oacc[nc] *= al;

      // P^T -> PL (packed b64, swizzled, wave-private rows)
#pragma unroll
      for (int ns = 0; ns < 4; ++ns) {
        uint2 pk;
        pk.x = pk2bf(ps[ns][0], ps[ns][1]);
        pk.y = pk2bf(ps[ns][2], ps[ns][3]);
        *(uint2*)(PL + pw_base + (((ns * 2 + pw_g) ^ c7) * 8)) = pk;
      }
      bf16x8 pf0 = *(const bf16x8*)(PL + rowq + chA0);
      bf16x8 pf1 = *(const bf16x8*)(PL + rowq + chA1);

      // O^T += V^T·P^T
#pragma unroll
      for (int nc = 0; nc < 4; ++nc) {
        bf16x8 vf0 = *(const bf16x8*)(Vc + nc * 1024 + rowc + chA0);
        bf16x8 vf1 = *(const bf16x8*)(Vc + nc * 1024 + rowc + chA1);
        oacc[nc] = mfma16(vf0, pf0, oacc[nc]);
        oacc[nc] = mfma16(vf1, pf1, oacc[nc]);
      }
      __syncthreads();                   // drains prefetch; frees cur buffers
    }

    // epilogue: normalize, O^T -> PL (transpose via LDS), coalesced store
    float linv = 1.f / l_i;
#pragma unroll
    for (int nc = 0; nc < 4; ++nc) {
      uint2 ok;
      ok.x = pk2bf(oacc[nc][0] * linv, oacc[nc][1] * linv);
      ok.y = pk2bf(oacc[nc][2] * linv, oacc[nc][3] * linv);
      *(uint2*)(PL + pw_base + (((nc * 2 + pw_g) ^ c7) * 8)) = ok;
    }
    __syncthreads();
#pragma unroll
    for (int i2 = 0; i2 < 2; ++i2) {
      int ch = tid + i2 * 256;
      int r = ch >> 3, g = ch & 7;
      size_t row = (size_t)b * 4096 + qt * 64 + r;
      *(int4*)&Oaug[row * KAUG + h * 64 + g * 8] =
          *(const int4*)(PL + r * 64 + ((g ^ (r & 7)) * 8));
    }
    __syncthreads();                     // PL reads done before next half's Q
  }
}

// ---------------- host launch ------------------------------------------------
extern "C" void kernel_launch(void* const* d_in, const int* in_sizes, int n_in,
                              void* d_out, int out_size, void* d_ws, size_t ws_size,
                              hipStream_t stream) {
  const float* x   = (const float*)d_in[0];
  const float* fc  = (const float*)d_in[1];
  const float* fs  = (const float*)d_in[2];
  // d_in[3] = mask (causal, reimplemented analytically)
  const float* wq  = (const float*)d_in[4];
  const float* wqb = (const float*)d_in[5];
  const float* wk  = (const float*)d_in[6];
  const float* wv  = (const float*)d_in[7];
  const float* wo  = (const float*)d_in[8];
  const float* wob = (const float*)d_in[9];
  const float* lq1 = (const float*)d_in[10];
  const float* lq2 = (const float*)d_in[11];
  const float* lk1 = (const float*)d_in[12];
  const float* lk2 = (const float*)d_in[13];
  const float* lv1 = (const float*)d_in[14];
  const float* lv2 = (const float*)d_in[15];
  const float* lo1 = (const float*)d_in[16];
  const float* lo2 = (const float*)d_in[17];

  char* ws = (char*)d_ws;
  const size_t OFF_XAUG  = 0;
  const size_t OFF_XOAUG = 17825792;
  const size_t OFF_WQKV  = 35651584;
  const size_t OFF_WOAUG = 42336256;
  const size_t OFF_L1CAT = 44564480;
  const size_t OFF_BIASC = 44695552;
  const size_t OFF_QB    = 44707840;
  const size_t OFF_KB    = 61485056;
  const size_t OFF_VT    = 78262272;

  short* xaug  = (short*)(ws + OFF_XAUG);
  short* xoaug = (short*)(ws + OFF_XOAUG);
  short* wqkv  = (short*)(ws + OFF_WQKV);
  short* woaug = (short*)(ws + OFF_WOAUG);
  short* l1cat = (short*)(ws + OFF_L1CAT);
  float* biasc = (float*)(ws + OFF_BIASC);
  short* qb    = (short*)(ws + OFF_QB);
  short* kb    = (short*)(ws + OFF_KB);
  short* vt    = (short*)(ws + OFF_VT);

  prep_k<<<50444, 256, 0, stream>>>(x, wq, wk, wv, wo, wqb,
                                    lq1, lq2, lk1, lk2, lv1, lv2, lo1, lo2,
                                    xaug, wqkv, woaug, l1cat, biasc);
  gemm_bt<1><<<dim3(1, 64), 256, 0, stream>>>(xaug, KAUG, l1cat, 1024, 48, 1024,
                                              nullptr, xaug, KAUG, 1024,
                                              nullptr, nullptr, nullptr);
  gemm_bt<2><<<dim3(24, 64), 256, 0, stream>>>(xaug, KAUG, wqkv, KAUG, 3072, KAUG,
                                               biasc, nullptr, 0, 0, qb, kb, vt);
  rope_k<<<32768, 256, 0, stream>>>(qb, kb, fc, fs);
  flash_k<<<dim3(32, 32), 256, 0, stream>>>(qb, kb, vt, xoaug);
  gemm_bt<1><<<dim3(1, 64), 256, 0, stream>>>(xoaug, KAUG, l1cat + 48 * 1024, 1024,
                                              16, 1024, nullptr, xoaug, KAUG, 1024,
                                              nullptr, nullptr, nullptr);
  gemm_bt<0><<<dim3(8, 64), 256, 0, stream>>>(xoaug, KAUG, woaug, KAUG, 1024, KAUG,
                                              wob, d_out, 1024, 0,
                                              nullptr, nullptr, nullptr);
}

// Round 5
// 464.937 us; speedup vs baseline: 1.5941x; 1.0647x over previous
//
#include <hip/hip_runtime.h>
#include <hip/hip_bf16.h>
#include <stdint.h>

// Problem constants
#define S_DIM 4096
#define D_DIM 1024
#define KAUG  1088          // 1024 + 64 (LoRA-augmented K)
#define M_ROWS 8192         // B*S

typedef short bf16x8 __attribute__((ext_vector_type(8)));
typedef float f32x4  __attribute__((ext_vector_type(4)));

__device__ __forceinline__ f32x4 mfma16(bf16x8 a, bf16x8 b, f32x4 c) {
  return __builtin_amdgcn_mfma_f32_16x16x32_bf16(a, b, c, 0, 0, 0);
}
// precise RNE (used only in memory-bound prep)
__device__ __forceinline__ short f2bs(float f) {
  __hip_bfloat16 h = __float2bfloat16(f);
  return *reinterpret_cast<short*>(&h);
}
// fast 2-op bf16 cast: +0x8000 round, take high half (<=1 ulp vs RNE on ties)
__device__ __forceinline__ short f2bs_fast(float f) {
  unsigned u = __builtin_bit_cast(unsigned, f) + 0x8000u;
  return (short)(u >> 16);
}
// fast packed pair: 2 adds + 1 v_perm_b32 (a -> low16, b -> high16)
__device__ __forceinline__ unsigned pk2bf(float a, float b) {
  unsigned ua = __builtin_bit_cast(unsigned, a) + 0x8000u;
  unsigned ub = __builtin_bit_cast(unsigned, b) + 0x8000u;
  return __builtin_amdgcn_perm(ub, ua, 0x07060302);
}
__device__ __forceinline__ float bs2f(short s) {
  __hip_bfloat16 h;
  *reinterpret_cast<short*>(&h) = s;
  return __bfloat162float(h);
}
__device__ __forceinline__ float fexp2(float x) {
  return __builtin_amdgcn_exp2f(x);   // single v_exp_f32
}
__device__ __forceinline__ void gload16(const void* g, void* l) {
  __builtin_amdgcn_global_load_lds(
      (const __attribute__((address_space(1))) unsigned int*)g,
      (__attribute__((address_space(3))) unsigned int*)l, 16, 0, 0);
}

// ---------------- prep: casts + augmented operand construction ----------------
__global__ void prep_k(const float* __restrict__ x,
                       const float* __restrict__ wq, const float* __restrict__ wk,
                       const float* __restrict__ wv, const float* __restrict__ wo,
                       const float* __restrict__ wqb,
                       const float* __restrict__ lq1, const float* __restrict__ lq2,
                       const float* __restrict__ lk1, const float* __restrict__ lk2,
                       const float* __restrict__ lv1, const float* __restrict__ lv2,
                       const float* __restrict__ lo1, const float* __restrict__ lo2,
                       short* __restrict__ xaug, short* __restrict__ wqkv,
                       short* __restrict__ woaug, short* __restrict__ l1cat,
                       float* __restrict__ biasc)
{
  unsigned i = blockIdx.x * 256u + threadIdx.x;
  if (i < 8388608u) {   // R1: x -> bf16 into xaug cols 0..1023
    unsigned m = i >> 10, k = i & 1023u;
    xaug[(size_t)m * KAUG + k] = f2bs(x[i]);
    return;
  }
  i -= 8388608u;
  if (i < 3342336u) {   // R2: wqkv_aug (3072 x 1088)
    unsigned n = i / 1088u, k = i - n * 1088u;
    float v;
    if (k < 1024u) {
      v = (n < 1024u) ? wq[n * 1024u + k]
        : (n < 2048u) ? wk[(n - 1024u) * 1024u + k]
                      : wv[(n - 2048u) * 1024u + k];
    } else {
      unsigned r = k - 1024u, blk = r >> 4, which = n >> 10;
      if (blk == which) {
        const float* l2 = which == 0 ? lq2 : which == 1 ? lk2 : lv2;
        v = l2[(n & 1023u) * 16u + (r & 15u)];
      } else v = 0.f;
    }
    wqkv[i] = f2bs(v);
    return;
  }
  i -= 3342336u;
  if (i < 1114112u) {   // R3: wo_aug (1024 x 1088)
    unsigned n = i / 1088u, k = i - n * 1088u;
    float v = (k < 1024u) ? wo[n * 1024u + k]
            : (k < 1040u) ? lo2[n * 16u + (k - 1024u)] : 0.f;
    woaug[i] = f2bs(v);
    return;
  }
  i -= 1114112u;
  if (i < 65536u) {     // R4: l1cat (64 x 1024)
    unsigned r = i >> 10, k = i & 1023u;
    const float* src = r < 16u ? lq1 : r < 32u ? lk1 : r < 48u ? lv1 : lo1;
    l1cat[i] = f2bs(src[(r & 15u) * 1024u + k]);
    return;
  }
  i -= 65536u;
  if (i < 3072u) {      // R5: bias_cat
    biasc[i] = (i < 1024u) ? wqb[i] : 0.f;
  }
}

// ---------------- GEMM: C[m,n] = sum_k A[m,k]*B[n,k]  (B^T layout) -----------
// MODE 0: fp32 out + bias   MODE 1: bf16 out at [m*ldc+colofs+n]
// MODE 2: QKV scatter: Q,K -> (B,H,S,HD); V -> transposed (B,H,HD,S) packed
template<int MODE>
__global__ __launch_bounds__(256) void gemm_bt(
    const short* __restrict__ A, int lda,
    const short* __restrict__ B, int ldb,
    int N, int K,
    const float* __restrict__ bias,
    void* __restrict__ Cout, int ldc, int colofs,
    short* __restrict__ qo, short* __restrict__ ko, short* __restrict__ vo)
{
  __shared__ short As[128 * 32];
  __shared__ short Bs[128 * 32];
  const int tid = threadIdx.x;
  const int w = tid >> 6, lane = tid & 63;
  const int q4 = lane >> 4, c = lane & 15;
  const int mh = w >> 1, nh = w & 1;
  const int mt = blockIdx.y, nt = blockIdx.x;

  const int rl = lane >> 2;          // 0..15
  const int kc = (lane & 3) * 8;

  const short* Ag0 = A + (size_t)(mt * 128 + w * 32 + rl) * lda + kc;
  const short* Ag1 = Ag0 + (size_t)16 * lda;
  int rb0 = nt * 128 + w * 32 + rl;      if (rb0 > N - 1) rb0 = N - 1;
  int rb1 = nt * 128 + w * 32 + 16 + rl; if (rb1 > N - 1) rb1 = N - 1;
  const short* Bg0 = B + (size_t)rb0 * ldb + kc;
  const short* Bg1 = B + (size_t)rb1 * ldb + kc;
  short* as0 = &As[(w * 32) * 32];
  short* as1 = &As[(w * 32 + 16) * 32];
  short* bs0 = &Bs[(w * 32) * 32];
  short* bs1 = &Bs[(w * 32 + 16) * 32];

  f32x4 acc[4][4];
#pragma unroll
  for (int ms = 0; ms < 4; ++ms)
#pragma unroll
    for (int ns = 0; ns < 4; ++ns) acc[ms][ns] = (f32x4){0.f, 0.f, 0.f, 0.f};

  const int nkt = K >> 5;
  for (int kt = 0; kt < nkt; ++kt) {
    __syncthreads();
    gload16(Ag0, as0);
    gload16(Ag1, as1);
    gload16(Bg0, bs0);
    gload16(Bg1, bs1);
    Ag0 += 32; Ag1 += 32; Bg0 += 32; Bg1 += 32;
    __syncthreads();
    bf16x8 af[4], bfr[4];
#pragma unroll
    for (int ms = 0; ms < 4; ++ms)
      af[ms] = *(const bf16x8*)&As[(mh * 64 + ms * 16 + c) * 32 + q4 * 8];
#pragma unroll
    for (int ns = 0; ns < 4; ++ns)
      bfr[ns] = *(const bf16x8*)&Bs[(nh * 64 + ns * 16 + c) * 32 + q4 * 8];
#pragma unroll
    for (int ms = 0; ms < 4; ++ms)
#pragma unroll
      for (int ns = 0; ns < 4; ++ns)
        acc[ms][ns] = mfma16(af[ms], bfr[ns], acc[ms][ns]);
  }

#pragma unroll
  for (int ms = 0; ms < 4; ++ms) {
#pragma unroll
    for (int ns = 0; ns < 4; ++ns) {
      const int n = nt * 128 + nh * 64 + ns * 16 + c;
      if (MODE == 0) {
        float bsv = (n < N) ? bias[n] : 0.f;
        float* Co = (float*)Cout;
#pragma unroll
        for (int r = 0; r < 4; ++r) {
          int m = mt * 128 + mh * 64 + ms * 16 + q4 * 4 + r;
          if (n < N) Co[(size_t)m * ldc + n] = acc[ms][ns][r] + bsv;
        }
      } else if (MODE == 1) {
        short* Co = (short*)Cout;
#pragma unroll
        for (int r = 0; r < 4; ++r) {
          int m = mt * 128 + mh * 64 + ms * 16 + q4 * 4 + r;
          if (n < N) Co[(size_t)m * ldc + colofs + n] = f2bs_fast(acc[ms][ns][r]);
        }
      } else {
        float bsv = bias[n];
        int which = n >> 10;
        int h = (n >> 6) & 15;
        int hd = n & 63;
        int m0 = mt * 128 + mh * 64 + ms * 16 + q4 * 4;
        int bb = m0 >> 12, s = m0 & 4095;
        if (which < 2) {
          short* dst = which == 0 ? qo : ko;
#pragma unroll
          for (int r = 0; r < 4; ++r)
            dst[(size_t)((bb * 16 + h) * 4096 + s + r) * 64 + hd] =
                f2bs_fast(acc[ms][ns][r] + bsv);
        } else {
          // V: write directly transposed (B,H,HD,S); 4 consecutive s -> 8B
          uint2 vk;
          vk.x = pk2bf(acc[ms][ns][0] + bsv, acc[ms][ns][1] + bsv);
          vk.y = pk2bf(acc[ms][ns][2] + bsv, acc[ms][ns][3] + bsv);
          *(uint2*)&vo[(((size_t)bb * 16 + h) * 64 + hd) * 4096 + s] = vk;
        }
      }
    }
  }
}

// ---------------- RoPE on Q,K in (B,H,S,HD) ---------------------------------
// Q scaled by (1/8)*log2(e) so flash can use exp2 directly.
__global__ void rope_k(short* __restrict__ Qb, short* __restrict__ Kb,
                       const float* __restrict__ cf, const float* __restrict__ sf)
{
  unsigned idx = blockIdx.x * 256u + threadIdx.x;   // total 8388608
  const unsigned half = 4194304u;                   // 32*4096*32
  bool isQ = idx < half;
  short* P = isQ ? Qb : Kb;
  unsigned r = idx & (half - 1u);
  unsigned bh = r >> 17;
  unsigned s = (r >> 5) & 4095u;
  unsigned i = r & 31u;
  size_t base = ((size_t)bh * 4096 + s) * 64 + 2u * i;
  unsigned pv = *(const unsigned*)&P[base];
  float e = bs2f((short)(pv & 0xFFFFu));
  float o = bs2f((short)(pv >> 16));
  float cc = cf[s * 32u + i], ss = sf[s * 32u + i];
  float re = e * cc - o * ss;
  float im = e * ss + o * cc;
  if (isQ) { re *= 0.18033688011112042f; im *= 0.18033688011112042f; }  // 0.125*log2e
  *(unsigned*)&P[base] = pk2bf(re, im);
}

// ---------------- Flash attention v3 (S^T structure, paired Q-tiles) ---------
// Each block handles qt = 63-bx (heavy) then qt = bx (light): uniform 65
// KV-iterations per block; grid = 1024 blocks = exactly 4/CU resident.
// S^T = K·Q^T (per-lane softmax state), O^T = V^T·P^T.
// LDS map (shorts): Kbuf0 @0, Kbuf1 @4096, Vbuf0 @8192, Vbuf1 @12288,
//                   PL @16384 (Q staging / P / O) = 40960 B total.
__global__ __launch_bounds__(256, 4) void flash_k(
    const short* __restrict__ Qb, const short* __restrict__ Kb,
    const short* __restrict__ Vt, short* __restrict__ Oaug)
{
  __shared__ short lds[20480];
  short* const PL = &lds[16384];

  const int bh = blockIdx.y;
  const int tid = threadIdx.x;
  const int w = tid >> 6, lane = tid & 63;
  const int q4 = lane >> 4, c = lane & 15;

  const short* Kg = Kb + (size_t)bh * 4096 * 64;
  const short* Vg = Vt + (size_t)bh * 64 * 4096;

  // staging source offsets (shorts), XOR-swizzled chunk layout
  const int l8 = lane >> 3, l7 = lane & 7;
  const int sw = (l7 ^ l8) * 8;
  const int G0 = w * 2, G1 = w * 2 + 1;
  const int koff0 = (G0 * 8 + l8) * 64 + sw;       // K/Q: row-major rows
  const int koff1 = (G1 * 8 + l8) * 64 + sw;
  const int voff0 = (G0 * 8 + l8) * 4096 + sw;     // V^T: hd-major rows
  const int voff1 = (G1 * 8 + l8) * 4096 + sw;

  // fragment read offsets (shorts)
  const int c7 = c & 7;
  const int chA0 = ((q4) ^ c7) * 8;                // k-chunk t=0
  const int chA1 = ((4 + q4) ^ c7) * 8;            // k-chunk t=1
  const int rowc = c * 64;                         // row = (blk*16 + c)
  const int rowq = (w * 16 + c) * 64;              // Q/P/O row for this wave
  const int pw_base = (w * 16 + c) * 64 + (q4 & 1) * 4;
  const int pw_g = q4 >> 1;

  const int b = bh >> 4, h = bh & 15;

  for (int half = 0; half < 2; ++half) {
    const int qt = half == 0 ? 63 - (int)blockIdx.x : (int)blockIdx.x;
    const short* Qg = Qb + ((size_t)bh * 4096 + qt * 64) * 64;

    // prologue: stage Q -> PL, K/V tile 0 -> buf0
    gload16(Qg + koff0, &lds[16384 + G0 * 512]);
    gload16(Qg + koff1, &lds[16384 + G1 * 512]);
    gload16(Kg + koff0, &lds[G0 * 512]);
    gload16(Kg + koff1, &lds[G1 * 512]);
    gload16(Vg + voff0, &lds[8192 + G0 * 512]);
    gload16(Vg + voff1, &lds[8192 + G1 * 512]);
    __syncthreads();

    bf16x8 qf0 = *(const bf16x8*)(PL + rowq + chA0);
    bf16x8 qf1 = *(const bf16x8*)(PL + rowq + chA1);

    f32x4 oacc[4];
#pragma unroll
    for (int i = 0; i < 4; ++i) oacc[i] = (f32x4){0.f, 0.f, 0.f, 0.f};
    float m_i = -1e30f, l_i = 0.f;

    for (int kt = 0; kt <= qt; ++kt) {
      const int cur = (kt & 1) * 4096;
      const short* Kc = &lds[cur];
      const short* Vc = &lds[8192 + cur];
      if (kt < qt) {                     // prefetch next tile (overlaps compute)
        const int nxt = ((kt + 1) & 1) * 4096;
        const short* ks = Kg + (size_t)(kt + 1) * 4096;
        const short* vs = Vg + (size_t)(kt + 1) * 64;
        gload16(ks + koff0, &lds[nxt + G0 * 512]);
        gload16(ks + koff1, &lds[nxt + G1 * 512]);
        gload16(vs + voff0, &lds[8192 + nxt + G0 * 512]);
        gload16(vs + voff1, &lds[8192 + nxt + G1 * 512]);
      }

      // S^T = K·Q^T : st[ns][r] = S(k = ns*16+q4*4+r, m = c)
      f32x4 st[4];
#pragma unroll
      for (int ns = 0; ns < 4; ++ns) {
        bf16x8 kf0 = *(const bf16x8*)(Kc + ns * 1024 + rowc + chA0);
        bf16x8 kf1 = *(const bf16x8*)(Kc + ns * 1024 + rowc + chA1);
        st[ns] = mfma16(kf0, qf0, (f32x4){0.f, 0.f, 0.f, 0.f});
        st[ns] = mfma16(kf1, qf1, st[ns]);
      }
      if (kt == qt) {                    // diagonal-block causal mask
#pragma unroll
        for (int ns = 0; ns < 4; ++ns)
#pragma unroll
          for (int r = 0; r < 4; ++r)
            if (ns * 16 + q4 * 4 + r > w * 16 + c) st[ns][r] = -1e30f;
      }

      // online softmax, per-lane state (row = c)
      float vm = st[0][0];
#pragma unroll
      for (int ns = 0; ns < 4; ++ns)
#pragma unroll
        for (int r = 0; r < 4; ++r) vm = fmaxf(vm, st[ns][r]);
      vm = fmaxf(vm, __shfl_xor(vm, 16));
      vm = fmaxf(vm, __shfl_xor(vm, 32));
      float mn = fmaxf(m_i, vm);
      float al = fexp2(m_i - mn);
      m_i = mn;

      float ps[4][4];
      float sum = 0.f;
#pragma unroll
      for (int ns = 0; ns < 4; ++ns)
#pragma unroll
        for (int r = 0; r < 4; ++r) {
          ps[ns][r] = fexp2(st[ns][r] - mn);
          sum += ps[ns][r];
        }
      sum += __shfl_xor(sum, 16);
      sum += __shfl_xor(sum, 32);
      l_i = l_i * al + sum;
#pragma unroll
      for (int nc = 0; nc < 4; ++nc) oacc[nc] *= al;

      // P^T -> PL (packed b64, swizzled, wave-private rows)
#pragma unroll
      for (int ns = 0; ns < 4; ++ns) {
        uint2 pk;
        pk.x = pk2bf(ps[ns][0], ps[ns][1]);
        pk.y = pk2bf(ps[ns][2], ps[ns][3]);
        *(uint2*)(PL + pw_base + (((ns * 2 + pw_g) ^ c7) * 8)) = pk;
      }
      bf16x8 pf0 = *(const bf16x8*)(PL + rowq + chA0);
      bf16x8 pf1 = *(const bf16x8*)(PL + rowq + chA1);

      // O^T += V^T·P^T
#pragma unroll
      for (int nc = 0; nc < 4; ++nc) {
        bf16x8 vf0 = *(const bf16x8*)(Vc + nc * 1024 + rowc + chA0);
        bf16x8 vf1 = *(const bf16x8*)(Vc + nc * 1024 + rowc + chA1);
        oacc[nc] = mfma16(vf0, pf0, oacc[nc]);
        oacc[nc] = mfma16(vf1, pf1, oacc[nc]);
      }
      __syncthreads();                   // drains prefetch; frees cur buffers
    }

    // epilogue: normalize, O^T -> PL (transpose via LDS), coalesced store
    float linv = 1.f / l_i;
#pragma unroll
    for (int nc = 0; nc < 4; ++nc) {
      uint2 ok;
      ok.x = pk2bf(oacc[nc][0] * linv, oacc[nc][1] * linv);
      ok.y = pk2bf(oacc[nc][2] * linv, oacc[nc][3] * linv);
      *(uint2*)(PL + pw_base + (((nc * 2 + pw_g) ^ c7) * 8)) = ok;
    }
    __syncthreads();
#pragma unroll
    for (int i2 = 0; i2 < 2; ++i2) {
      int ch = tid + i2 * 256;
      int r = ch >> 3, g = ch & 7;
      size_t row = (size_t)b * 4096 + qt * 64 + r;
      *(int4*)&Oaug[row * KAUG + h * 64 + g * 8] =
          *(const int4*)(PL + r * 64 + ((g ^ (r & 7)) * 8));
    }
    __syncthreads();                     // PL reads done before next half's Q
  }
}

// ---------------- host launch ------------------------------------------------
extern "C" void kernel_launch(void* const* d_in, const int* in_sizes, int n_in,
                              void* d_out, int out_size, void* d_ws, size_t ws_size,
                              hipStream_t stream) {
  const float* x   = (const float*)d_in[0];
  const float* fc  = (const float*)d_in[1];
  const float* fs  = (const float*)d_in[2];
  // d_in[3] = mask (causal, reimplemented analytically)
  const float* wq  = (const float*)d_in[4];
  const float* wqb = (const float*)d_in[5];
  const float* wk  = (const float*)d_in[6];
  const float* wv  = (const float*)d_in[7];
  const float* wo  = (const float*)d_in[8];
  const float* wob = (const float*)d_in[9];
  const float* lq1 = (const float*)d_in[10];
  const float* lq2 = (const float*)d_in[11];
  const float* lk1 = (const float*)d_in[12];
  const float* lk2 = (const float*)d_in[13];
  const float* lv1 = (const float*)d_in[14];
  const float* lv2 = (const float*)d_in[15];
  const float* lo1 = (const float*)d_in[16];
  const float* lo2 = (const float*)d_in[17];

  char* ws = (char*)d_ws;
  const size_t OFF_XAUG  = 0;
  const size_t OFF_XOAUG = 17825792;
  const size_t OFF_WQKV  = 35651584;
  const size_t OFF_WOAUG = 42336256;
  const size_t OFF_L1CAT = 44564480;
  const size_t OFF_BIASC = 44695552;
  const size_t OFF_QB    = 44707840;
  const size_t OFF_KB    = 61485056;
  const size_t OFF_VT    = 78262272;

  short* xaug  = (short*)(ws + OFF_XAUG);
  short* xoaug = (short*)(ws + OFF_XOAUG);
  short* wqkv  = (short*)(ws + OFF_WQKV);
  short* woaug = (short*)(ws + OFF_WOAUG);
  short* l1cat = (short*)(ws + OFF_L1CAT);
  float* biasc = (float*)(ws + OFF_BIASC);
  short* qb    = (short*)(ws + OFF_QB);
  short* kb    = (short*)(ws + OFF_KB);
  short* vt    = (short*)(ws + OFF_VT);

  prep_k<<<50444, 256, 0, stream>>>(x, wq, wk, wv, wo, wqb,
                                    lq1, lq2, lk1, lk2, lv1, lv2, lo1, lo2,
                                    xaug, wqkv, woaug, l1cat, biasc);
  gemm_bt<1><<<dim3(1, 64), 256, 0, stream>>>(xaug, KAUG, l1cat, 1024, 48, 1024,
                                              nullptr, xaug, KAUG, 1024,
                                              nullptr, nullptr, nullptr);
  gemm_bt<2><<<dim3(24, 64), 256, 0, stream>>>(xaug, KAUG, wqkv, KAUG, 3072, KAUG,
                                               biasc, nullptr, 0, 0, qb, kb, vt);
  rope_k<<<32768, 256, 0, stream>>>(qb, kb, fc, fs);
  flash_k<<<dim3(32, 32), 256, 0, stream>>>(qb, kb, vt, xoaug);
  gemm_bt<1><<<dim3(1, 64), 256, 0, stream>>>(xoaug, KAUG, l1cat + 48 * 1024, 1024,
                                              16, 1024, nullptr, xoaug, KAUG, 1024,
                                              nullptr, nullptr, nullptr);
  gemm_bt<0><<<dim3(8, 64), 256, 0, stream>>>(xoaug, KAUG, woaug, KAUG, 1024, KAUG,
                                              wob, d_out, 1024, 0,
                                              nullptr, nullptr, nullptr);
}

// Round 6
// 440.574 us; speedup vs baseline: 1.6823x; 1.0553x over previous
//
#include <hip/hip_runtime.h>
#include <hip/hip_bf16.h>
#include <stdint.h>

// Problem constants
#define S_DIM 4096
#define D_DIM 1024
#define KAUG  1088          // 1024 + 64 (LoRA-augmented K)
#define M_ROWS 8192         // B*S

typedef short bf16x8 __attribute__((ext_vector_type(8)));
typedef float f32x4  __attribute__((ext_vector_type(4)));

__device__ __forceinline__ f32x4 mfma16(bf16x8 a, bf16x8 b, f32x4 c) {
  return __builtin_amdgcn_mfma_f32_16x16x32_bf16(a, b, c, 0, 0, 0);
}
// precise RNE (used only in memory-bound prep)
__device__ __forceinline__ short f2bs(float f) {
  __hip_bfloat16 h = __float2bfloat16(f);
  return *reinterpret_cast<short*>(&h);
}
// fast 2-op bf16 cast: +0x8000 round, take high half (<=1 ulp vs RNE on ties)
__device__ __forceinline__ short f2bs_fast(float f) {
  unsigned u = __builtin_bit_cast(unsigned, f) + 0x8000u;
  return (short)(u >> 16);
}
// fast packed pair: 2 adds + 1 v_perm_b32 (a -> low16, b -> high16)
__device__ __forceinline__ unsigned pk2bf(float a, float b) {
  unsigned ua = __builtin_bit_cast(unsigned, a) + 0x8000u;
  unsigned ub = __builtin_bit_cast(unsigned, b) + 0x8000u;
  return __builtin_amdgcn_perm(ub, ua, 0x07060302);
}
__device__ __forceinline__ float bs2f(short s) {
  __hip_bfloat16 h;
  *reinterpret_cast<short*>(&h) = s;
  return __bfloat162float(h);
}
__device__ __forceinline__ float fexp2(float x) {
  return __builtin_amdgcn_exp2f(x);   // single v_exp_f32
}
__device__ __forceinline__ void gload16(const void* g, void* l) {
  __builtin_amdgcn_global_load_lds(
      (const __attribute__((address_space(1))) unsigned int*)g,
      (__attribute__((address_space(3))) unsigned int*)l, 16, 0, 0);
}

// ---------------- prep: casts + augmented operand construction ----------------
//  R1 xaug cols 0..1023 <- bf16(x)              8388608
//  R2 wqkv_aug (3072 x 1088)                    3342336
//  R3 wo_aug  (1024 x 1088)                     1114112
//  R4 l1cat   (64 x 1024)                       65536
//  R5 bias_cat (3072)                           3072
//  R6 cs2 interleaved float2 cos/sin table      131072
__global__ void prep_k(const float* __restrict__ x,
                       const float* __restrict__ wq, const float* __restrict__ wk,
                       const float* __restrict__ wv, const float* __restrict__ wo,
                       const float* __restrict__ wqb,
                       const float* __restrict__ lq1, const float* __restrict__ lq2,
                       const float* __restrict__ lk1, const float* __restrict__ lk2,
                       const float* __restrict__ lv1, const float* __restrict__ lv2,
                       const float* __restrict__ lo1, const float* __restrict__ lo2,
                       const float* __restrict__ cf, const float* __restrict__ sf,
                       short* __restrict__ xaug, short* __restrict__ wqkv,
                       short* __restrict__ woaug, short* __restrict__ l1cat,
                       float* __restrict__ biasc, float* __restrict__ cs2)
{
  unsigned i = blockIdx.x * 256u + threadIdx.x;
  if (i < 8388608u) {   // R1: x -> bf16 into xaug cols 0..1023
    unsigned m = i >> 10, k = i & 1023u;
    xaug[(size_t)m * KAUG + k] = f2bs(x[i]);
    return;
  }
  i -= 8388608u;
  if (i < 3342336u) {   // R2: wqkv_aug (3072 x 1088)
    unsigned n = i / 1088u, k = i - n * 1088u;
    float v;
    if (k < 1024u) {
      v = (n < 1024u) ? wq[n * 1024u + k]
        : (n < 2048u) ? wk[(n - 1024u) * 1024u + k]
                      : wv[(n - 2048u) * 1024u + k];
    } else {
      unsigned r = k - 1024u, blk = r >> 4, which = n >> 10;
      if (blk == which) {
        const float* l2 = which == 0 ? lq2 : which == 1 ? lk2 : lv2;
        v = l2[(n & 1023u) * 16u + (r & 15u)];
      } else v = 0.f;
    }
    wqkv[i] = f2bs(v);
    return;
  }
  i -= 3342336u;
  if (i < 1114112u) {   // R3: wo_aug (1024 x 1088)
    unsigned n = i / 1088u, k = i - n * 1088u;
    float v = (k < 1024u) ? wo[n * 1024u + k]
            : (k < 1040u) ? lo2[n * 16u + (k - 1024u)] : 0.f;
    woaug[i] = f2bs(v);
    return;
  }
  i -= 1114112u;
  if (i < 65536u) {     // R4: l1cat (64 x 1024)
    unsigned r = i >> 10, k = i & 1023u;
    const float* src = r < 16u ? lq1 : r < 32u ? lk1 : r < 48u ? lv1 : lo1;
    l1cat[i] = f2bs(src[(r & 15u) * 1024u + k]);
    return;
  }
  i -= 65536u;
  if (i < 3072u) {      // R5: bias_cat
    biasc[i] = (i < 1024u) ? wqb[i] : 0.f;
    return;
  }
  i -= 3072u;
  if (i < 131072u) {    // R6: interleaved cos/sin
    cs2[2u * i]     = cf[i];
    cs2[2u * i + 1] = sf[i];
  }
}

// ---------------- GEMM: C[m,n] = sum_k A[m,k]*B[n,k]  (B^T layout) -----------
// MODE 0: fp32 out + bias   MODE 1: bf16 out at [m*ldc+colofs+n]
// MODE 2: QKV scatter with FUSED RoPE on Q,K (Q also scaled by 0.125*log2e);
//         Q,K -> (B,H,S,HD); V -> transposed (B,H,HD,S) packed
template<int MODE>
__global__ __launch_bounds__(256) void gemm_bt(
    const short* __restrict__ A, int lda,
    const short* __restrict__ B, int ldb,
    int N, int K,
    const float* __restrict__ bias,
    void* __restrict__ Cout, int ldc, int colofs,
    short* __restrict__ qo, short* __restrict__ ko, short* __restrict__ vo,
    const float* __restrict__ cs2)
{
  __shared__ short As[128 * 32];
  __shared__ short Bs[128 * 32];
  const int tid = threadIdx.x;
  const int w = tid >> 6, lane = tid & 63;
  const int q4 = lane >> 4, c = lane & 15;
  const int mh = w >> 1, nh = w & 1;
  const int mt = blockIdx.y, nt = blockIdx.x;

  const int rl = lane >> 2;          // 0..15
  const int kc = (lane & 3) * 8;

  const short* Ag0 = A + (size_t)(mt * 128 + w * 32 + rl) * lda + kc;
  const short* Ag1 = Ag0 + (size_t)16 * lda;
  int rb0 = nt * 128 + w * 32 + rl;      if (rb0 > N - 1) rb0 = N - 1;
  int rb1 = nt * 128 + w * 32 + 16 + rl; if (rb1 > N - 1) rb1 = N - 1;
  const short* Bg0 = B + (size_t)rb0 * ldb + kc;
  const short* Bg1 = B + (size_t)rb1 * ldb + kc;
  short* as0 = &As[(w * 32) * 32];
  short* as1 = &As[(w * 32 + 16) * 32];
  short* bs0 = &Bs[(w * 32) * 32];
  short* bs1 = &Bs[(w * 32 + 16) * 32];

  f32x4 acc[4][4];
#pragma unroll
  for (int ms = 0; ms < 4; ++ms)
#pragma unroll
    for (int ns = 0; ns < 4; ++ns) acc[ms][ns] = (f32x4){0.f, 0.f, 0.f, 0.f};

  const int nkt = K >> 5;
  for (int kt = 0; kt < nkt; ++kt) {
    __syncthreads();
    gload16(Ag0, as0);
    gload16(Ag1, as1);
    gload16(Bg0, bs0);
    gload16(Bg1, bs1);
    Ag0 += 32; Ag1 += 32; Bg0 += 32; Bg1 += 32;
    __syncthreads();
    bf16x8 af[4], bfr[4];
#pragma unroll
    for (int ms = 0; ms < 4; ++ms)
      af[ms] = *(const bf16x8*)&As[(mh * 64 + ms * 16 + c) * 32 + q4 * 8];
#pragma unroll
    for (int ns = 0; ns < 4; ++ns)
      bfr[ns] = *(const bf16x8*)&Bs[(nh * 64 + ns * 16 + c) * 32 + q4 * 8];
#pragma unroll
    for (int ms = 0; ms < 4; ++ms)
#pragma unroll
      for (int ns = 0; ns < 4; ++ns)
        acc[ms][ns] = mfma16(af[ms], bfr[ns], acc[ms][ns]);
  }

#pragma unroll
  for (int ms = 0; ms < 4; ++ms) {
#pragma unroll
    for (int ns = 0; ns < 4; ++ns) {
      const int n = nt * 128 + nh * 64 + ns * 16 + c;
      if (MODE == 0) {
        float bsv = (n < N) ? bias[n] : 0.f;
        float* Co = (float*)Cout;
#pragma unroll
        for (int r = 0; r < 4; ++r) {
          int m = mt * 128 + mh * 64 + ms * 16 + q4 * 4 + r;
          if (n < N) Co[(size_t)m * ldc + n] = acc[ms][ns][r] + bsv;
        }
      } else if (MODE == 1) {
        short* Co = (short*)Cout;
#pragma unroll
        for (int r = 0; r < 4; ++r) {
          int m = mt * 128 + mh * 64 + ms * 16 + q4 * 4 + r;
          if (n < N) Co[(size_t)m * ldc + colofs + n] = f2bs_fast(acc[ms][ns][r]);
        }
      } else {
        float bsv = bias[n];
        int which = n >> 10;                  // wave-uniform per (nt,nh,ns)
        int m0 = mt * 128 + mh * 64 + ms * 16 + q4 * 4;
        int bb = m0 >> 12, spos = m0 & 4095;
        if (which < 2) {
          // fused RoPE: pair (even hd, odd hd) = adjacent lanes (c even/odd)
          int h = (n >> 6) & 15;
          int hd = n & 63;
          short* dst = which == 0 ? qo : ko;
          const float sgn = (c & 1) ? 1.f : -1.f;
          const int ihalf = hd >> 1;          // same for the lane pair
#pragma unroll
          for (int r = 0; r < 4; ++r) {
            float val = acc[ms][ns][r] + bsv;
            float part = __shfl_xor(val, 1);
            float2 cs = *(const float2*)&cs2[((size_t)(spos + r) * 32 + ihalf) * 2];
            // even lane: re = val*cc - part*ss ; odd lane: im = part*ss + val*cc
            float res = val * cs.x + part * (sgn * cs.y);
            if (which == 0) res *= 0.18033688011112042f;   // 0.125*log2e
            dst[(size_t)((bb * 16 + h) * 4096 + spos + r) * 64 + hd] = f2bs_fast(res);
          }
        } else {
          // V: write directly transposed (B,H,HD,S); 4 consecutive s -> 8B
          int h = (n >> 6) & 15;
          int hd = n & 63;
          uint2 vk;
          vk.x = pk2bf(acc[ms][ns][0] + bsv, acc[ms][ns][1] + bsv);
          vk.y = pk2bf(acc[ms][ns][2] + bsv, acc[ms][ns][3] + bsv);
          *(uint2*)&vo[(((size_t)bb * 16 + h) * 64 + hd) * 4096 + spos] = vk;
        }
      }
    }
  }
}

// ---------------- small-N skinny GEMM: BM=64, grid = M/64 blocks -------------
// C[m, colofs+n] = sum_k A[m,k]*B[n,k], N <= NT*16, bf16 out.
template<int NT>
__global__ __launch_bounds__(256) void tgemm_k(
    const short* __restrict__ A, int lda,
    const short* __restrict__ B, int ldb,
    int N, int K, short* __restrict__ C, int ldc, int colofs)
{
  __shared__ short As[64 * 32];
  __shared__ short Bs[64 * 32];
  const int tid = threadIdx.x;
  const int w = tid >> 6, lane = tid & 63;
  const int q4 = lane >> 4, c = lane & 15;
  const int rl = lane >> 2, kc = (lane & 3) * 8;
  const int arow = w * 16 + rl;
  const int brow = arow <= N - 1 ? arow : N - 1;

  const short* Ag = A + (size_t)(blockIdx.x * 64 + arow) * lda + kc;
  const short* Bg = B + (size_t)brow * ldb + kc;
  short* asd = &As[(w * 16) * 32];
  short* bsd = &Bs[(w * 16) * 32];

  f32x4 acc[NT];
#pragma unroll
  for (int i = 0; i < NT; ++i) acc[i] = (f32x4){0.f, 0.f, 0.f, 0.f};

  const int nkt = K >> 5;
  for (int kt = 0; kt < nkt; ++kt) {
    __syncthreads();
    gload16(Ag, asd);
    gload16(Bg, bsd);
    Ag += 32; Bg += 32;
    __syncthreads();
    bf16x8 af = *(const bf16x8*)&As[(w * 16 + c) * 32 + q4 * 8];
#pragma unroll
    for (int nsi = 0; nsi < NT; ++nsi) {
      bf16x8 bf = *(const bf16x8*)&Bs[(nsi * 16 + c) * 32 + q4 * 8];
      acc[nsi] = mfma16(af, bf, acc[nsi]);
    }
  }
#pragma unroll
  for (int nsi = 0; nsi < NT; ++nsi) {
#pragma unroll
    for (int r = 0; r < 4; ++r) {
      int m = blockIdx.x * 64 + w * 16 + q4 * 4 + r;
      int n = nsi * 16 + c;
      if (n < N) C[(size_t)m * ldc + colofs + n] = f2bs_fast(acc[nsi][r]);
    }
  }
}

// ---------------- Flash attention v3 (S^T structure, paired Q-tiles) ---------
// Each block handles qt = 63-bx (heavy) then qt = bx (light): uniform 65
// KV-iterations per block; grid = 1024 blocks = exactly 4/CU resident.
// S^T = K·Q^T (per-lane softmax state), O^T = V^T·P^T.
// LDS map (shorts): Kbuf0 @0, Kbuf1 @4096, Vbuf0 @8192, Vbuf1 @12288,
//                   PL @16384 (Q staging / P / O) = 40960 B total.
__global__ __launch_bounds__(256, 4) void flash_k(
    const short* __restrict__ Qb, const short* __restrict__ Kb,
    const short* __restrict__ Vt, short* __restrict__ Oaug)
{
  __shared__ short lds[20480];
  short* const PL = &lds[16384];

  const int bh = blockIdx.y;
  const int tid = threadIdx.x;
  const int w = tid >> 6, lane = tid & 63;
  const int q4 = lane >> 4, c = lane & 15;

  const short* Kg = Kb + (size_t)bh * 4096 * 64;
  const short* Vg = Vt + (size_t)bh * 64 * 4096;

  // staging source offsets (shorts), XOR-swizzled chunk layout
  const int l8 = lane >> 3, l7 = lane & 7;
  const int sw = (l7 ^ l8) * 8;
  const int G0 = w * 2, G1 = w * 2 + 1;
  const int koff0 = (G0 * 8 + l8) * 64 + sw;       // K/Q: row-major rows
  const int koff1 = (G1 * 8 + l8) * 64 + sw;
  const int voff0 = (G0 * 8 + l8) * 4096 + sw;     // V^T: hd-major rows
  const int voff1 = (G1 * 8 + l8) * 4096 + sw;

  // fragment read offsets (shorts)
  const int c7 = c & 7;
  const int chA0 = ((q4) ^ c7) * 8;                // k-chunk t=0
  const int chA1 = ((4 + q4) ^ c7) * 8;            // k-chunk t=1
  const int rowc = c * 64;                         // row = (blk*16 + c)
  const int rowq = (w * 16 + c) * 64;              // Q/P/O row for this wave
  const int pw_base = (w * 16 + c) * 64 + (q4 & 1) * 4;
  const int pw_g = q4 >> 1;

  const int b = bh >> 4, h = bh & 15;

  for (int half = 0; half < 2; ++half) {
    const int qt = half == 0 ? 63 - (int)blockIdx.x : (int)blockIdx.x;
    const short* Qg = Qb + ((size_t)bh * 4096 + qt * 64) * 64;

    // prologue: stage Q -> PL, K/V tile 0 -> buf0
    gload16(Qg + koff0, &lds[16384 + G0 * 512]);
    gload16(Qg + koff1, &lds[16384 + G1 * 512]);
    gload16(Kg + koff0, &lds[G0 * 512]);
    gload16(Kg + koff1, &lds[G1 * 512]);
    gload16(Vg + voff0, &lds[8192 + G0 * 512]);
    gload16(Vg + voff1, &lds[8192 + G1 * 512]);
    __syncthreads();

    bf16x8 qf0 = *(const bf16x8*)(PL + rowq + chA0);
    bf16x8 qf1 = *(const bf16x8*)(PL + rowq + chA1);

    f32x4 oacc[4];
#pragma unroll
    for (int i = 0; i < 4; ++i) oacc[i] = (f32x4){0.f, 0.f, 0.f, 0.f};
    float m_i = -1e30f, l_i = 0.f;

    for (int kt = 0; kt <= qt; ++kt) {
      const int cur = (kt & 1) * 4096;
      const short* Kc = &lds[cur];
      const short* Vc = &lds[8192 + cur];
      if (kt < qt) {                     // prefetch next tile (overlaps compute)
        const int nxt = ((kt + 1) & 1) * 4096;
        const short* ks = Kg + (size_t)(kt + 1) * 4096;
        const short* vs = Vg + (size_t)(kt + 1) * 64;
        gload16(ks + koff0, &lds[nxt + G0 * 512]);
        gload16(ks + koff1, &lds[nxt + G1 * 512]);
        gload16(vs + voff0, &lds[8192 + nxt + G0 * 512]);
        gload16(vs + voff1, &lds[8192 + nxt + G1 * 512]);
      }

      // S^T = K·Q^T : st[ns][r] = S(k = ns*16+q4*4+r, m = c)
      f32x4 st[4];
#pragma unroll
      for (int ns = 0; ns < 4; ++ns) {
        bf16x8 kf0 = *(const bf16x8*)(Kc + ns * 1024 + rowc + chA0);
        bf16x8 kf1 = *(const bf16x8*)(Kc + ns * 1024 + rowc + chA1);
        st[ns] = mfma16(kf0, qf0, (f32x4){0.f, 0.f, 0.f, 0.f});
        st[ns] = mfma16(kf1, qf1, st[ns]);
      }
      if (kt == qt) {                    // diagonal-block causal mask
#pragma unroll
        for (int ns = 0; ns < 4; ++ns)
#pragma unroll
          for (int r = 0; r < 4; ++r)
            if (ns * 16 + q4 * 4 + r > w * 16 + c) st[ns][r] = -1e30f;
      }

      // online softmax, per-lane state (row = c)
      float vm = st[0][0];
#pragma unroll
      for (int ns = 0; ns < 4; ++ns)
#pragma unroll
        for (int r = 0; r < 4; ++r) vm = fmaxf(vm, st[ns][r]);
      vm = fmaxf(vm, __shfl_xor(vm, 16));
      vm = fmaxf(vm, __shfl_xor(vm, 32));
      float mn = fmaxf(m_i, vm);
      float al = fexp2(m_i - mn);
      m_i = mn;

      float ps[4][4];
      float sum = 0.f;
#pragma unroll
      for (int ns = 0; ns < 4; ++ns)
#pragma unroll
        for (int r = 0; r < 4; ++r) {
          ps[ns][r] = fexp2(st[ns][r] - mn);
          sum += ps[ns][r];
        }
      sum += __shfl_xor(sum, 16);
      sum += __shfl_xor(sum, 32);
      l_i = l_i * al + sum;
#pragma unroll
      for (int nc = 0; nc < 4; ++nc) oacc[nc] *= al;

      // P^T -> PL (packed b64, swizzled, wave-private rows)
#pragma unroll
      for (int ns = 0; ns < 4; ++ns) {
        uint2 pk;
        pk.x = pk2bf(ps[ns][0], ps[ns][1]);
        pk.y = pk2bf(ps[ns][2], ps[ns][3]);
        *(uint2*)(PL + pw_base + (((ns * 2 + pw_g) ^ c7) * 8)) = pk;
      }
      bf16x8 pf0 = *(const bf16x8*)(PL + rowq + chA0);
      bf16x8 pf1 = *(const bf16x8*)(PL + rowq + chA1);

      // O^T += V^T·P^T
#pragma unroll
      for (int nc = 0; nc < 4; ++nc) {
        bf16x8 vf0 = *(const bf16x8*)(Vc + nc * 1024 + rowc + chA0);
        bf16x8 vf1 = *(const bf16x8*)(Vc + nc * 1024 + rowc + chA1);
        oacc[nc] = mfma16(vf0, pf0, oacc[nc]);
        oacc[nc] = mfma16(vf1, pf1, oacc[nc]);
      }
      __syncthreads();                   // drains prefetch; frees cur buffers
    }

    // epilogue: normalize, O^T -> PL (transpose via LDS), coalesced store
    float linv = 1.f / l_i;
#pragma unroll
    for (int nc = 0; nc < 4; ++nc) {
      uint2 ok;
      ok.x = pk2bf(oacc[nc][0] * linv, oacc[nc][1] * linv);
      ok.y = pk2bf(oacc[nc][2] * linv, oacc[nc][3] * linv);
      *(uint2*)(PL + pw_base + (((nc * 2 + pw_g) ^ c7) * 8)) = ok;
    }
    __syncthreads();
#pragma unroll
    for (int i2 = 0; i2 < 2; ++i2) {
      int ch = tid + i2 * 256;
      int r = ch >> 3, g = ch & 7;
      size_t row = (size_t)b * 4096 + qt * 64 + r;
      *(int4*)&Oaug[row * KAUG + h * 64 + g * 8] =
          *(const int4*)(PL + r * 64 + ((g ^ (r & 7)) * 8));
    }
    __syncthreads();                     // PL reads done before next half's Q
  }
}

// ---------------- host launch ------------------------------------------------
extern "C" void kernel_launch(void* const* d_in, const int* in_sizes, int n_in,
                              void* d_out, int out_size, void* d_ws, size_t ws_size,
                              hipStream_t stream) {
  const float* x   = (const float*)d_in[0];
  const float* fc  = (const float*)d_in[1];
  const float* fs  = (const float*)d_in[2];
  // d_in[3] = mask (causal, reimplemented analytically)
  const float* wq  = (const float*)d_in[4];
  const float* wqb = (const float*)d_in[5];
  const float* wk  = (const float*)d_in[6];
  const float* wv  = (const float*)d_in[7];
  const float* wo  = (const float*)d_in[8];
  const float* wob = (const float*)d_in[9];
  const float* lq1 = (const float*)d_in[10];
  const float* lq2 = (const float*)d_in[11];
  const float* lk1 = (const float*)d_in[12];
  const float* lk2 = (const float*)d_in[13];
  const float* lv1 = (const float*)d_in[14];
  const float* lv2 = (const float*)d_in[15];
  const float* lo1 = (const float*)d_in[16];
  const float* lo2 = (const float*)d_in[17];

  char* ws = (char*)d_ws;
  const size_t OFF_XAUG  = 0;
  const size_t OFF_XOAUG = 17825792;
  const size_t OFF_WQKV  = 35651584;
  const size_t OFF_WOAUG = 42336256;
  const size_t OFF_L1CAT = 44564480;
  const size_t OFF_BIASC = 44695552;
  const size_t OFF_QB    = 44707840;
  const size_t OFF_KB    = 61485056;
  const size_t OFF_VT    = 78262272;
  const size_t OFF_CS    = 95039488;   // 131072 float2 = 1 MiB

  short* xaug  = (short*)(ws + OFF_XAUG);
  short* xoaug = (short*)(ws + OFF_XOAUG);
  short* wqkv  = (short*)(ws + OFF_WQKV);
  short* woaug = (short*)(ws + OFF_WOAUG);
  short* l1cat = (short*)(ws + OFF_L1CAT);
  float* biasc = (float*)(ws + OFF_BIASC);
  short* qb    = (short*)(ws + OFF_QB);
  short* kb    = (short*)(ws + OFF_KB);
  short* vt    = (short*)(ws + OFF_VT);
  float* cs2   = (float*)(ws + OFF_CS);

  // 13044736 elements total = exactly 50956 blocks
  prep_k<<<50956, 256, 0, stream>>>(x, wq, wk, wv, wo, wqb,
                                    lq1, lq2, lk1, lk2, lv1, lv2, lo1, lo2,
                                    fc, fs,
                                    xaug, wqkv, woaug, l1cat, biasc, cs2);
  // T_qkv = x @ [lq1;lk1;lv1]^T -> xaug cols 1024..1071 (128 blocks)
  tgemm_k<3><<<128, 256, 0, stream>>>(xaug, KAUG, l1cat, 1024, 48, 1024,
                                      xaug, KAUG, 1024);
  // fused QKV projection + bias + RoPE -> qb,kb (B,H,S,HD), vt (B,H,HD,S)
  gemm_bt<2><<<dim3(24, 64), 256, 0, stream>>>(xaug, KAUG, wqkv, KAUG, 3072, KAUG,
                                               biasc, nullptr, 0, 0, qb, kb, vt,
                                               cs2);
  // flash attention -> xoaug cols 0..1023
  flash_k<<<dim3(32, 32), 256, 0, stream>>>(qb, kb, vt, xoaug);
  // T_o = attn_out @ lo1^T -> xoaug cols 1024..1039 (128 blocks)
  tgemm_k<1><<<128, 256, 0, stream>>>(xoaug, KAUG, l1cat + 48 * 1024, 1024,
                                      16, 1024, xoaug, KAUG, 1024);
  // final projection -> d_out (fp32)
  gemm_bt<0><<<dim3(8, 64), 256, 0, stream>>>(xoaug, KAUG, woaug, KAUG, 1024, KAUG,
                                              wob, d_out, 1024, 0,
                                              nullptr, nullptr, nullptr, nullptr);
}